// Round 24
// baseline (469.406 us; speedup 1.0000x reference)
//
#include <hip/hip_runtime.h>

// ---------------------------------------------------------------------------
// Conformer block, MI355X gfx950. Inputs/outputs fp32; internal activations
// bf16 with fp32 accumulation via bf16 MFMA 16x16x32.
// Round 24: LDS bank-conflict fix (T2/T21) in conv_tap/gemm_bdw/gemm_bd.
// A-tile rows are 64B (half a bank period); reads put each quarter-wave on
// 2/8 bank-quads (8 lanes/quad). Fix: store row r chunk c at granule
// c ^ ((r>>1)&3) via pre-swizzled GLOBAL source (LDS dest stays linear for
// global_load_lds), swizzle the ds_read address identically. Placement-only:
// bitwise-identical math. Rest frozen at round 23.
// ---------------------------------------------------------------------------

typedef __attribute__((ext_vector_type(4))) float f32x4;
typedef __attribute__((ext_vector_type(8))) short short8;
typedef __attribute__((ext_vector_type(4))) short s16x4;

__device__ __forceinline__ float bfs2f(short s) {
  unsigned u = ((unsigned)(unsigned short)s) << 16;
  float f; __builtin_memcpy(&f, &u, 4); return f;
}
__device__ __forceinline__ short f2bfs(float f) {
  unsigned u; __builtin_memcpy(&u, &f, 4);
  u = (u + 0x7FFFu + ((u >> 16) & 1u)) >> 16;   // RNE
  return (short)u;
}
__device__ __forceinline__ float sigmoidf_(float x) { return 1.f / (1.f + __expf(-x)); }

#define GLOADLDS(gsrc, ldst) \
  __builtin_amdgcn_global_load_lds((__attribute__((address_space(1))) void*)(gsrc), \
                                   (__attribute__((address_space(3))) void*)(ldst), 16, 0, 0)

#define VMCNT_ASM(n) asm volatile("s_waitcnt vmcnt(" #n ")" ::: "memory")
template<int N> __device__ __forceinline__ void vmcnt_wait() {
  if      constexpr (N == 0)  VMCNT_ASM(0);
  else if constexpr (N == 2)  VMCNT_ASM(2);
  else if constexpr (N == 3)  VMCNT_ASM(3);
  else if constexpr (N == 4)  VMCNT_ASM(4);
  else if constexpr (N == 5)  VMCNT_ASM(5);
  else if constexpr (N == 6)  VMCNT_ASM(6);
  else if constexpr (N == 8)  VMCNT_ASM(8);
  else if constexpr (N == 12) VMCNT_ASM(12);
  else                        VMCNT_ASM(0);
}
#define MEMFENCE asm volatile("" ::: "memory")

enum { EPI_SILU = 0, EPI_BBIAS = 1, EPI_QKV = 3 };

// ---------------------------------------------------------------------------
// B-direct wide GEMM: C[8192][NB*128] = f(A.B^T + bias). LDS A swizzled:
// row r chunk c stored at granule c^((r>>1)&3).
// ---------------------------------------------------------------------------
template<int NB, int EPI>
__global__ __launch_bounds__(256) void gemm_bdw(
    const short* __restrict__ A,
    const short* __restrict__ wBP,
    const float* __restrict__ bias,
    const float* __restrict__ bias2,
    const float* __restrict__ bias3,
    short* __restrict__ C)
{
  constexpr int NT = 16;
  constexpr int LDC = NB * 128;
  __shared__ short sA[3][128 * 32];
  const int tid = threadIdx.x;
  const int m0 = (int)blockIdx.x * 128, n0 = (int)blockIdx.y * 128;
  const int lane = tid & 63, wid = tid >> 6;
  const int wm = wid >> 1, wn = wid & 1;
  const int lr = lane & 15, kgr = lane >> 4;
  const int aRow = wm * 64, bRow = wn * 64;
  const int aCol = (kgr ^ ((lr >> 1) & 3)) * 8;   // swizzled read granule
  const long NSTR = (long)NT * 512;
  const short* Bp = wBP + (long)((n0 + bRow) >> 4) * NSTR + lane * 8;

  auto stageA = [&](int buf, int t) {
#pragma unroll
    for (int it = 0; it < 2; ++it) {
      int idx = it * 256 + tid;
      int row = idx >> 2;
      int csrc = (idx & 3) ^ ((row >> 1) & 3);    // pre-swizzled source chunk
      GLOADLDS(A + (long)(m0 + row) * 512 + t * 32 + csrc * 8, &sA[buf][idx * 8]);
    }
  };

  f32x4 acc[4][4];
#pragma unroll
  for (int i = 0; i < 4; ++i) {
#pragma unroll
    for (int j = 0; j < 4; ++j) acc[i][j] = (f32x4){0.f, 0.f, 0.f, 0.f};
  }
  short8 b0[4], b1[4];

  stageA(0, 0);
  stageA(1, 1);
  MEMFENCE;
#pragma unroll
  for (int ni = 0; ni < 4; ++ni)
    b0[ni] = *(const short8*)(Bp + ni * NSTR);
  MEMFENCE;
  vmcnt_wait<6>();
  __builtin_amdgcn_s_barrier();

  int rd = 0;
  for (int t = 0; t < NT; t += 2) {
    {
      int wr = rd - 1; if (wr < 0) wr += 3;
      if (t + 2 < NT) stageA(wr, t + 2);
      MEMFENCE;
#pragma unroll
      for (int ni = 0; ni < 4; ++ni)
        b1[ni] = *(const short8*)(Bp + (long)(t + 1) * 512 + ni * NSTR);
      MEMFENCE;
      short8 af[4];
#pragma unroll
      for (int mi = 0; mi < 4; ++mi)
        af[mi] = *(const short8*)&sA[rd][(aRow + mi * 16 + lr) * 32 + aCol];
      __builtin_amdgcn_s_setprio(1);
#pragma unroll
      for (int mi = 0; mi < 4; ++mi) {
#pragma unroll
        for (int ni = 0; ni < 4; ++ni)
          acc[mi][ni] = __builtin_amdgcn_mfma_f32_16x16x32_bf16(af[mi], b0[ni], acc[mi][ni], 0, 0, 0);
      }
      __builtin_amdgcn_s_setprio(0);
      if (t + 2 < NT) vmcnt_wait<6>(); else vmcnt_wait<4>();
      __builtin_amdgcn_s_barrier();
      rd = (rd == 2) ? 0 : rd + 1;
    }
    {
      int wr = rd - 1; if (wr < 0) wr += 3;
      if (t + 3 < NT) stageA(wr, t + 3);
      MEMFENCE;
      if (t + 2 < NT) {
#pragma unroll
        for (int ni = 0; ni < 4; ++ni)
          b0[ni] = *(const short8*)(Bp + (long)(t + 2) * 512 + ni * NSTR);
      }
      MEMFENCE;
      short8 af[4];
#pragma unroll
      for (int mi = 0; mi < 4; ++mi)
        af[mi] = *(const short8*)&sA[rd][(aRow + mi * 16 + lr) * 32 + aCol];
      __builtin_amdgcn_s_setprio(1);
#pragma unroll
      for (int mi = 0; mi < 4; ++mi) {
#pragma unroll
        for (int ni = 0; ni < 4; ++ni)
          acc[mi][ni] = __builtin_amdgcn_mfma_f32_16x16x32_bf16(af[mi], b1[ni], acc[mi][ni], 0, 0, 0);
      }
      __builtin_amdgcn_s_setprio(0);
      if (t + 3 < NT) vmcnt_wait<6>(); else vmcnt_wait<0>();
      __builtin_amdgcn_s_barrier();
      rd = (rd == 2) ? 0 : rd + 1;
    }
  }

  const int baseRow = m0 + aRow, baseCol = n0 + bRow;
#pragma unroll
  for (int mi = 0; mi < 4; ++mi) {
#pragma unroll
    for (int ni = 0; ni < 4; ++ni) {
      const int col = baseCol + ni * 16 + lr;
#pragma unroll
      for (int r = 0; r < 4; ++r) {
        const int row = baseRow + mi * 16 + kgr * 4 + r;
        float v = acc[mi][ni][r];
        if (EPI == EPI_SILU) {
          v += bias[col];
          v = v * sigmoidf_(v);
          C[(long)row * LDC + col] = f2bfs(v);
        } else if (EPI == EPI_BBIAS) {
          v += bias[col];
          C[(long)row * LDC + col] = f2bfs(v);
        } else if (EPI == EPI_QKV) {
          if (col < 512)       v = (v + bias[col]) * 0.125f;
          else if (col < 1024) v += bias2[col - 512];
          else                 v += bias3[col - 1024];
          C[(long)row * LDC + col] = f2bfs(v);
        }
      }
    }
  }
}

// ---------------------------------------------------------------------------
// B-direct GEMM for N=512 residual outputs; same LDS A swizzle.
// ---------------------------------------------------------------------------
template<int NT>
__global__ __launch_bounds__(256) void gemm_bd(
    const short* __restrict__ A,
    const short* __restrict__ wBP,
    const float* __restrict__ bias,
    const float* __restrict__ resid,
    float* __restrict__ C,
    float alpha, float beta)
{
  constexpr int K = NT * 32;
  __shared__ short sA[3][64 * 32];
  const int tid = threadIdx.x;
  const int x = (int)blockIdx.x >> 2, y = (int)blockIdx.x & 3;
  const int m0 = x * 64, n0 = y * 128;
  const int lane = tid & 63, wid = tid >> 6;
  const int wm = wid >> 1, wn = wid & 1;
  const int lr = lane & 15, kgr = lane >> 4;
  const int aRow = wm * 32, bRow = wn * 64;
  const int aCol = (kgr ^ ((lr >> 1) & 3)) * 8;   // swizzled read granule
  const long NSTR = (long)NT * 512;
  const short* Bp = wBP + (long)((n0 + bRow) >> 4) * NSTR + lane * 8;

  auto stageA = [&](int buf, int t) {
    int row = tid >> 2;
    int csrc = (tid & 3) ^ ((row >> 1) & 3);
    GLOADLDS(A + (long)(m0 + row) * K + t * 32 + csrc * 8, &sA[buf][tid * 8]);
  };

  f32x4 acc[2][4];
#pragma unroll
  for (int i = 0; i < 2; ++i) {
#pragma unroll
    for (int j = 0; j < 4; ++j) acc[i][j] = (f32x4){0.f, 0.f, 0.f, 0.f};
  }
  short8 b0[4], b1[4];

  stageA(0, 0);
  stageA(1, 1);
  MEMFENCE;
#pragma unroll
  for (int ni = 0; ni < 4; ++ni)
    b0[ni] = *(const short8*)(Bp + ni * NSTR);
  MEMFENCE;
  vmcnt_wait<5>();
  __builtin_amdgcn_s_barrier();

  int rd = 0;
  for (int t = 0; t < NT; t += 2) {
    {
      int wr = rd - 1; if (wr < 0) wr += 3;
      if (t + 2 < NT) stageA(wr, t + 2);
      MEMFENCE;
#pragma unroll
      for (int ni = 0; ni < 4; ++ni)
        b1[ni] = *(const short8*)(Bp + (long)(t + 1) * 512 + ni * NSTR);
      MEMFENCE;
      short8 af[2];
#pragma unroll
      for (int mi = 0; mi < 2; ++mi)
        af[mi] = *(const short8*)&sA[rd][(aRow + mi * 16 + lr) * 32 + aCol];
      __builtin_amdgcn_s_setprio(1);
#pragma unroll
      for (int mi = 0; mi < 2; ++mi) {
#pragma unroll
        for (int ni = 0; ni < 4; ++ni)
          acc[mi][ni] = __builtin_amdgcn_mfma_f32_16x16x32_bf16(af[mi], b0[ni], acc[mi][ni], 0, 0, 0);
      }
      __builtin_amdgcn_s_setprio(0);
      if (t + 2 < NT) vmcnt_wait<5>(); else vmcnt_wait<4>();
      __builtin_amdgcn_s_barrier();
      rd = (rd == 2) ? 0 : rd + 1;
    }
    {
      int wr = rd - 1; if (wr < 0) wr += 3;
      if (t + 3 < NT) stageA(wr, t + 3);
      MEMFENCE;
      if (t + 2 < NT) {
#pragma unroll
        for (int ni = 0; ni < 4; ++ni)
          b0[ni] = *(const short8*)(Bp + (long)(t + 2) * 512 + ni * NSTR);
      }
      MEMFENCE;
      short8 af[2];
#pragma unroll
      for (int mi = 0; mi < 2; ++mi)
        af[mi] = *(const short8*)&sA[rd][(aRow + mi * 16 + lr) * 32 + aCol];
      __builtin_amdgcn_s_setprio(1);
#pragma unroll
      for (int mi = 0; mi < 2; ++mi) {
#pragma unroll
        for (int ni = 0; ni < 4; ++ni)
          acc[mi][ni] = __builtin_amdgcn_mfma_f32_16x16x32_bf16(af[mi], b1[ni], acc[mi][ni], 0, 0, 0);
      }
      __builtin_amdgcn_s_setprio(0);
      if (t + 3 < NT) vmcnt_wait<5>(); else vmcnt_wait<0>();
      __builtin_amdgcn_s_barrier();
      rd = (rd == 2) ? 0 : rd + 1;
    }
  }

  const int baseRow = m0 + aRow, baseCol = n0 + bRow;
#pragma unroll
  for (int mi = 0; mi < 2; ++mi) {
#pragma unroll
    for (int ni = 0; ni < 4; ++ni) {
      const int col = baseCol + ni * 16 + lr;
#pragma unroll
      for (int r = 0; r < 4; ++r) {
        const int row = baseRow + mi * 16 + kgr * 4 + r;
        float v = acc[mi][ni][r] + bias[col];
        float rv = resid[(long)row * 512 + col];
        C[(long)row * 512 + col] = alpha * rv + beta * v;
      }
    }
  }
}

// ---------------------------------------------------------------------------
// ONE-SHOT prologue (round 23, frozen).
// ---------------------------------------------------------------------------
__global__ __launch_bounds__(256) void pack_all(
    const float* __restrict__ ff1_w1, const float* __restrict__ ff1_w2,
    const float* __restrict__ wq, const float* __restrict__ wk,
    const float* __restrict__ wv, const float* __restrict__ wo,
    const float* __restrict__ cv_w1, const float* __restrict__ cv_w2,
    const float* __restrict__ ff2_w1, const float* __restrict__ ff2_w2,
    const float* __restrict__ cv_wd,
    short* __restrict__ ff1w1P, short* __restrict__ ff1w2P,
    short* __restrict__ qkvP, short* __restrict__ woP,
    short* __restrict__ cw1P, short* __restrict__ cw2P,
    short* __restrict__ ff2w1P, short* __restrict__ ff2w2P,
    short* __restrict__ wdP, float* __restrict__ pe, float* __restrict__ stats)
{
  int bid = (int)blockIdx.x;
  const int tid = threadIdx.x;

  if (bid < 4096) {
    const int gid = bid * 256 + tid;
    const int n = gid >> 9, k = gid & 511;
    const float v = ff1_w1[((long)k << 11) | n];
    ff1w1P[((long)(n >> 4) * 16 + (k >> 5)) * 512 + ((k >> 3) & 3) * 128 + (n & 15) * 8 + (k & 7)] = f2bfs(v);
    return;
  }
  bid -= 4096;
  if (bid < 4096) {
    const int gid = bid * 256 + tid;
    const int n = gid >> 11, k = gid & 2047;
    const float v = ff1_w2[(long)k * 512 + n];
    ff1w2P[((long)((n >> 4) << 6) + (k >> 5)) * 512 + ((k >> 3) & 3) * 128 + (n & 15) * 8 + (k & 7)] = f2bfs(v);
    return;
  }
  bid -= 4096;
  if (bid < 3072) {
    const int gid = bid * 256 + tid;
    const int n = gid >> 9, k = gid & 511;
    const int sel = n >> 9;
    const int nn = n & 511;
    const float* w = (sel == 0) ? wq : (sel == 1) ? wk : wv;
    const float v = w[(long)(nn >> 6) * 32768 + (long)k * 64 + (nn & 63)];
    qkvP[((long)(n >> 4) * 16 + (k >> 5)) * 512 + ((k >> 3) & 3) * 128 + (n & 15) * 8 + (k & 7)] = f2bfs(v);
    return;
  }
  bid -= 3072;
  if (bid < 1024) {
    const int gid = bid * 256 + tid;
    const int n = gid >> 9, k = gid & 511;
    const float v = wo[(long)k * 512 + n];
    woP[((long)((n >> 4) << 4) + (k >> 5)) * 512 + ((k >> 3) & 3) * 128 + (n & 15) * 8 + (k & 7)] = f2bfs(v);
    return;
  }
  bid -= 1024;
  if (bid < 2048) {
    const int gid = bid * 256 + tid;
    const int n = gid >> 9, k = gid & 511;
    const float v = cv_w1[((long)n << 9) | k];
    cw1P[((long)(n >> 4) * 16 + (k >> 5)) * 512 + ((k >> 3) & 3) * 128 + (n & 15) * 8 + (k & 7)] = f2bfs(v);
    return;
  }
  bid -= 2048;
  if (bid < 1024) {
    const int gid = bid * 256 + tid;
    const int n = gid >> 9, k = gid & 511;
    const float v = cv_w2[((long)n << 9) | k];
    cw2P[((long)((n >> 4) << 4) + (k >> 5)) * 512 + ((k >> 3) & 3) * 128 + (n & 15) * 8 + (k & 7)] = f2bfs(v);
    return;
  }
  bid -= 1024;
  if (bid < 4096) {
    const int gid = bid * 256 + tid;
    const int n = gid >> 9, k = gid & 511;
    const float v = ff2_w1[((long)k << 11) | n];
    ff2w1P[((long)(n >> 4) * 16 + (k >> 5)) * 512 + ((k >> 3) & 3) * 128 + (n & 15) * 8 + (k & 7)] = f2bfs(v);
    return;
  }
  bid -= 4096;
  if (bid < 4096) {
    const int gid = bid * 256 + tid;
    const int n = gid >> 11, k = gid & 2047;
    const float v = ff2_w2[(long)k * 512 + n];
    ff2w2P[((long)((n >> 4) << 6) + (k >> 5)) * 512 + ((k >> 3) & 3) * 128 + (n & 15) * 8 + (k & 7)] = f2bfs(v);
    return;
  }
  bid -= 4096;
  if (bid < 1024) {
    const int gid = bid * 256 + tid;
    const int e = gid >> 9, i = gid & 511;
    const float* src = cv_wd + ((long)e * 512 + i) * 31;
    const long rowtile = (long)(e >> 4) * (512L * 512);
    const int inner = ((i >> 3) & 3) * 128 + (e & 15) * 8 + (i & 7);
#pragma unroll
    for (int KK = 0; KK < 31; ++KK)
      wdP[rowtile + (long)(KK * 16 + (i >> 5)) * 512 + inner] = f2bfs(src[KK]);
    wdP[rowtile + (long)(31 * 16 + (i >> 5)) * 512 + inner] = 0;
    return;
  }
  bid -= 1024;
  if (bid < 1024) {
    const int gid = bid * 256 + tid;
    const int t = gid >> 8, p = gid & 255;
    const float freq = __expf(-(float)p * (9.210340371976184f / 256.f));
    const float ang = (float)t * freq;
    pe[(long)t * 512 + 2 * p]     = sinf(ang);
    pe[(long)t * 512 + 2 * p + 1] = cosf(ang);
    return;
  }
  *(f32x4*)&stats[tid * 4] = (f32x4){0.f, 0.f, 0.f, 0.f};
}

// ---------------------------------------------------------------------------
// Conv, tap-tiled, B-prefetch depth 3; LDS A swizzled (kk-dependent read).
// ---------------------------------------------------------------------------
__global__ __launch_bounds__(256) void conv_tap(
    const short* __restrict__ glu,
    const short* __restrict__ wdP,
    short* __restrict__ parts)
{
  __shared__ short sA[2][144 * 32];
  const int tid = threadIdx.x;
  const int bid = blockIdx.x;
  const int cc = bid & 7, j = bid >> 3;
  const int y = cc >> 1, kg = cc & 1;
  const int x = j & 7, b = j >> 3;
  const int m0 = x * 128, n0 = y * 128;
  const short* Arow0 = glu + ((long)b * 1056 + m0 + 1 + kg * 16) * 512;
  short* cbase = parts + (long)kg * (8192L * 512) + (long)b * (1024L * 512);

  const int lane = tid & 63, wid = tid >> 6;
  const int wm = wid >> 1, wn = wid & 1;
  const int lr = lane & 15, kgr = lane >> 4;
  const int aRow = wm * 64, bRow = wn * 64;

  const short* Bp = wdP + (long)((n0 + bRow) >> 4) * (512L * 512)
                  + (long)(kg * 256) * 512 + lane * 8;
  const long NSTR = 512L * 512;

  auto stageA = [&](int buf, int ib) {
#pragma unroll
    for (int it = 0; it < 3; ++it) {
      int idx = it * 256 + tid;
      if (idx < 576) {
        int row = idx >> 2;
        int csrc = (idx & 3) ^ ((row >> 1) & 3);   // pre-swizzled source chunk
        GLOADLDS(Arow0 + (long)row * 512 + ib * 32 + csrc * 8,
                 &sA[buf][idx * 8]);
      }
    }
  };

  f32x4 acc[4][4];
#pragma unroll
  for (int i = 0; i < 4; ++i) {
#pragma unroll
    for (int jj = 0; jj < 4; ++jj) acc[i][jj] = (f32x4){0.f, 0.f, 0.f, 0.f};
  }
  short8 bfr[4][4];

#define LOADB(slot_, s_)                                                     \
  {                                                                          \
    const int s2 = (s_);                                                     \
    const long noff = (long)(((s2 & 15) * 16 + (s2 >> 4))) * 512;            \
    _Pragma("unroll")                                                        \
    for (int ni = 0; ni < 4; ++ni)                                           \
      bfr[slot_][ni] = *(const short8*)(Bp + noff + ni * NSTR);              \
  }

  stageA(0, 0);
  MEMFENCE;
  LOADB(0, 0); LOADB(1, 1); LOADB(2, 2);
  MEMFENCE;
  vmcnt_wait<12>();
  __builtin_amdgcn_s_barrier();

  int cur = 0;
  for (int ib = 0; ib < 16; ++ib) {
    if (ib + 1 < 16) stageA(cur ^ 1, ib + 1);
    MEMFENCE;
#pragma unroll
    for (int kk = 0; kk < 16; ++kk) {
      const int s = ib * 16 + kk;
      LOADB((kk + 3) & 3, s + 3);
      MEMFENCE;
      // row = kk + aRow + mi*16 + lr; bits 1..2 depend only on (kk+lr)
      const int aColk = (kgr ^ (((kk + lr) >> 1) & 3)) * 8;
      short8 af[4];
#pragma unroll
      for (int mi = 0; mi < 4; ++mi)
        af[mi] = *(const short8*)&sA[cur][(kk + aRow + mi * 16 + lr) * 32 + aColk];
      __builtin_amdgcn_s_setprio(1);
#pragma unroll
      for (int mi = 0; mi < 4; ++mi) {
#pragma unroll
        for (int ni = 0; ni < 4; ++ni)
          acc[mi][ni] = __builtin_amdgcn_mfma_f32_16x16x32_bf16(af[mi], bfr[kk & 3][ni], acc[mi][ni], 0, 0, 0);
      }
      __builtin_amdgcn_s_setprio(0);
    }
    vmcnt_wait<12>();
    __builtin_amdgcn_s_barrier();
    cur ^= 1;
  }
  vmcnt_wait<0>();
#undef LOADB

  const int baseRow = m0 + aRow, baseCol = n0 + bRow;
#pragma unroll
  for (int mi = 0; mi < 4; ++mi) {
#pragma unroll
    for (int ni = 0; ni < 4; ++ni) {
      const int col = baseCol + ni * 16 + lr;
#pragma unroll
      for (int r = 0; r < 4; ++r) {
        const int row = baseRow + mi * 16 + kgr * 4 + r;
        cbase[(long)row * 512 + col] = f2bfs(acc[mi][ni][r]);
      }
    }
  }
}

// ---------------------------------------------------------------------------
// Flash attention, XCD-pinned flat grid 1024 (round 22, frozen).
// ---------------------------------------------------------------------------
__global__ __launch_bounds__(256) void flash_attn(
    const short* __restrict__ qkv,
    const short* __restrict__ vt,
    short* __restrict__ out)
{
  __shared__ short sQ[64 * 64];
  __shared__ short sK[64 * 64];
  __shared__ short sV[64 * 64];
  __shared__ short sP[4][16 * 64];
  const int tid = threadIdx.x;
  const int lane = tid & 63, w = tid >> 6;
  const int lr = lane & 15, kg = lane >> 4;
  const int bid = (int)blockIdx.x;
  const int xcd = bid & 7, j = bid >> 3;
  const int bhi = j & 7, xq = j >> 3;
  const int bh = bhi * 8 + xcd;
  const int b = bh >> 3, h = bh & 7;
  const int q0 = xq * 64;
  const short* qbase = qkv + (long)b * 1024 * 1536 + h * 64;
  const short* kbase = qbase + 512;
  const short* vtb = vt + (long)bh * 65536;

#pragma unroll
  for (int it = 0; it < 2; ++it) {
    int idx = it * 256 + tid;
    int row = idx >> 3, c = (idx & 7) ^ (row & 7);
    GLOADLDS(qbase + (long)(q0 + row) * 1536 + c * 8, &sQ[idx * 8]);
  }
  __syncthreads();
  short8 bq[2];
#pragma unroll
  for (int ks = 0; ks < 2; ++ks)
    bq[ks] = *(const short8*)&sQ[(w * 16 + lr) * 64 + ((ks * 4 + kg) ^ (lr & 7)) * 8];

  f32x4 po[4];
#pragma unroll
  for (int mi = 0; mi < 4; ++mi) po[mi] = (f32x4){0.f, 0.f, 0.f, 0.f};
  float m = -3.0e38f, l = 0.f;

  for (int s0 = 0; s0 < 1024; s0 += 64) {
#pragma unroll
    for (int it = 0; it < 2; ++it) {
      int idx = it * 256 + tid;
      int row = idx >> 3, c = (idx & 7) ^ (row & 7);
      GLOADLDS(kbase + (long)(s0 + row) * 1536 + c * 8, &sK[idx * 8]);
    }
#pragma unroll
    for (int it = 0; it < 2; ++it) {
      int idx = it * 256 + tid;
      int row = idx >> 3, c = (idx & 7) ^ (row & 7);
      GLOADLDS(vtb + (long)row * 1024 + s0 + c * 8, &sV[idx * 8]);
    }
    __syncthreads();

    f32x4 as[4];
#pragma unroll
    for (int mi = 0; mi < 4; ++mi) as[mi] = (f32x4){0.f, 0.f, 0.f, 0.f};
    __builtin_amdgcn_s_setprio(1);
#pragma unroll
    for (int ks = 0; ks < 2; ++ks) {
#pragma unroll
      for (int mi = 0; mi < 4; ++mi) {
        short8 ak = *(const short8*)&sK[(mi * 16 + lr) * 64 + ((ks * 4 + kg) ^ (lr & 7)) * 8];
        as[mi] = __builtin_amdgcn_mfma_f32_16x16x32_bf16(ak, bq[ks], as[mi], 0, 0, 0);
      }
    }
    __builtin_amdgcn_s_setprio(0);

    float rmax = as[0][0];
#pragma unroll
    for (int mi = 0; mi < 4; ++mi) {
#pragma unroll
      for (int r = 0; r < 4; ++r) rmax = fmaxf(rmax, as[mi][r]);
    }
    rmax = fmaxf(rmax, __shfl_xor(rmax, 16));
    rmax = fmaxf(rmax, __shfl_xor(rmax, 32));
    const float mn = fmaxf(m, rmax);
    const float sc = __expf(m - mn);
    float p[4][4];
    float rsum = 0.f;
#pragma unroll
    for (int mi = 0; mi < 4; ++mi) {
#pragma unroll
      for (int r = 0; r < 4; ++r) { p[mi][r] = __expf(as[mi][r] - mn); rsum += p[mi][r]; }
    }
    rsum += __shfl_xor(rsum, 16);
    rsum += __shfl_xor(rsum, 32);
    l = l * sc + rsum;
    m = mn;
#pragma unroll
    for (int mi = 0; mi < 4; ++mi) {
#pragma unroll
      for (int r = 0; r < 4; ++r) po[mi][r] *= sc;
    }
#pragma unroll
    for (int mi = 0; mi < 4; ++mi) {
      s16x4 pk;
#pragma unroll
      for (int r = 0; r < 4; ++r) pk[r] = f2bfs(p[mi][r]);
      *(s16x4*)&sP[w][lr * 64 + ((mi ^ (lr & 3)) * 16 + kg * 4)] = pk;
    }
    __builtin_amdgcn_s_setprio(1);
#pragma unroll
    for (int ks = 0; ks < 2; ++ks) {
      short8 bp = *(const short8*)&sP[w][lr * 64 + (((ks * 2 + (kg >> 1)) ^ (lr & 3)) * 16 + (kg & 1) * 8)];
#pragma unroll
      for (int mi = 0; mi < 4; ++mi) {
        short8 av = *(const short8*)&sV[(mi * 16 + lr) * 64 + ((ks * 4 + kg) ^ (lr & 7)) * 8];
        po[mi] = __builtin_amdgcn_mfma_f32_16x16x32_bf16(av, bp, po[mi], 0, 0, 0);
      }
    }
    __builtin_amdgcn_s_setprio(0);
    __syncthreads();
  }

  const float inv = 1.f / l;
  const int t2 = q0 + w * 16 + lr;
  const int n = h * 1024 + t2;
  short* ob = out + ((long)b * 1024 + (n >> 3)) * 512 + (n & 7) * 64;
#pragma unroll
  for (int mi = 0; mi < 4; ++mi) {
    s16x4 o;
#pragma unroll
    for (int r = 0; r < 4; ++r) o[r] = f2bfs(po[mi][r] * inv);
    *(s16x4*)&ob[mi * 16 + kg * 4] = o;
  }
}

// ---------------------------------------------------------------------------
__global__ __launch_bounds__(256) void reduce_bn(
    const short* __restrict__ parts, long pstride,
    short* __restrict__ z, float* stats)
{
  const int r0 = blockIdx.x * 16;
  const int c = threadIdx.x * 2;
  float s0 = 0.f, s1 = 0.f, q0 = 0.f, q1 = 0.f;
#pragma unroll 4
  for (int r = 0; r < 16; ++r) {
    const long idx = (long)(r0 + r) * 512 + c;
    int p0 = *(const int*)&parts[idx];
    int p1 = *(const int*)&parts[idx + pstride];
    float a0 = bfs2f((short)(p0 & 0xffff)) + bfs2f((short)(p1 & 0xffff));
    float a1 = bfs2f((short)(p0 >> 16)) + bfs2f((short)(p1 >> 16));
    int zo = ((int)(unsigned short)f2bfs(a0)) | (((int)(unsigned short)f2bfs(a1)) << 16);
    *(int*)&z[idx] = zo;
    s0 += a0; s1 += a1; q0 += a0 * a0; q1 += a1 * a1;
  }
  atomicAdd(&stats[c], s0);
  atomicAdd(&stats[c + 1], s1);
  atomicAdd(&stats[512 + c], q0);
  atomicAdd(&stats[512 + c + 1], q1);
}

// ---------------------------------------------------------------------------
template<int ADDPE, int OUTF32>
__global__ __launch_bounds__(256) void ln_rows(
    const float* __restrict__ X, const float* __restrict__ g, const float* __restrict__ b,
    const float* __restrict__ pe, void* __restrict__ Y)
{
  const int row = blockIdx.x * 4 + (threadIdx.x >> 6);
  const int lane = threadIdx.x & 63;
  const int c0 = lane * 8;
  const float* src = X + (long)row * 512 + c0;
  f32x4 a = *(const f32x4*)src, c = *(const f32x4*)(src + 4);
  float x[8] = {a[0], a[1], a[2], a[3], c[0], c[1], c[2], c[3]};
  float s = 0.f, q = 0.f;
#pragma unroll
  for (int j = 0; j < 8; ++j) { s += x[j]; q += x[j] * x[j]; }
#pragma unroll
  for (int off = 32; off > 0; off >>= 1) { s += __shfl_xor(s, off); q += __shfl_xor(q, off); }
  const float mean = s * (1.f / 512.f);
  const float var = q * (1.f / 512.f) - mean * mean;
  const float rstd = rsqrtf(var + 1e-5f);
  f32x4 g0 = *(const f32x4*)(g + c0), g1 = *(const f32x4*)(g + c0 + 4);
  f32x4 b0 = *(const f32x4*)(b + c0), b1 = *(const f32x4*)(b + c0 + 4);
  float gg[8] = {g0[0], g0[1], g0[2], g0[3], g1[0], g1[1], g1[2], g1[3]};
  float bb[8] = {b0[0], b0[1], b0[2], b0[3], b1[0], b1[1], b1[2], b1[3]};
  float y[8];
#pragma unroll
  for (int j = 0; j < 8; ++j) {
    y[j] = (x[j] - mean) * rstd * gg[j] + bb[j];
    if (ADDPE) y[j] += pe[(long)(row & 1023) * 512 + c0 + j];
  }
  if (OUTF32) {
    float* dst = (float*)Y + (long)row * 512 + c0;
    *(f32x4*)dst = (f32x4){y[0], y[1], y[2], y[3]};
    *(f32x4*)(dst + 4) = (f32x4){y[4], y[5], y[6], y[7]};
  } else {
    short8 o;
#pragma unroll
    for (int j = 0; j < 8; ++j) o[j] = f2bfs(y[j]);
    *(short8*)((short*)Y + (long)row * 512 + c0) = o;
  }
}

// ---------------------------------------------------------------------------
__global__ __launch_bounds__(256) void transpose64b(
    const short* __restrict__ in, int ldin, short* __restrict__ out, int ldout,
    int zshift, long zh_in, long zl_in, long z_out)
{
  __shared__ short t[64][72];
  const int z = blockIdx.z;
  const long inoff = (long)(z >> zshift) * zh_in + (long)(z & ((1 << zshift) - 1)) * zl_in;
  const int tr = blockIdx.x;
  const short* src = in + inoff + (long)(tr * 64) * ldin;
  short* dst = out + (long)z * z_out + tr * 64;
  const int tid = threadIdx.x;
#pragma unroll
  for (int p = 0; p < 2; ++p) {
    int idx = p * 256 + tid;
    int r = idx >> 3, c8 = (idx & 7) * 8;
    short8 v = *(const short8*)(src + (long)r * ldin + c8);
#pragma unroll
    for (int j = 0; j < 8; ++j) t[r][c8 + j] = v[j];
  }
  __syncthreads();
#pragma unroll
  for (int p = 0; p < 2; ++p) {
    int idx = p * 256 + tid;
    int c = idx >> 3, r8 = (idx & 7) * 8;
    short8 v;
#pragma unroll
    for (int j = 0; j < 8; ++j) v[j] = t[r8 + j][c];
    *(short8*)(dst + (long)c * ldout + r8) = v;
  }
}

// ---------------------------------------------------------------------------
// glu + halo zero, fused (round 23, frozen).
// ---------------------------------------------------------------------------
__global__ __launch_bounds__(256) void glu_fused(const short* __restrict__ y1, short* __restrict__ gp)
{
  const int bb = (int)blockIdx.x;
  const int tid = threadIdx.x;
  if (bb < 4096) {
    const int gid = bb * 256 + tid;
    const int row = gid >> 7;
    const int ci = (gid & 127) * 4;
    const short* base = y1 + (long)row * 1024;
    s16x4 a = *(const s16x4*)(base + ci);
    s16x4 g = *(const s16x4*)(base + 512 + ci);
    const int b = row >> 10, t = row & 1023;
    s16x4 o;
#pragma unroll
    for (int j = 0; j < 4; ++j) o[j] = f2bfs(bfs2f(a[j]) * sigmoidf_(bfs2f(g[j])));
    *(s16x4*)(gp + ((long)b * 1056 + 16 + t) * 512 + ci) = o;
    return;
  }
  const int gid = (bb - 4096) * 256 + tid;
  if (gid >= 16512) return;
  long row;
  int c8;
  if (gid < 16384) {
    const int b = gid >> 11;
    const int r = (gid >> 6) & 31;
    c8 = (gid & 63) * 8;
    row = (long)b * 1056 + ((r < 16) ? r : (1024 + r));
  } else {
    const int k = gid - 16384;
    c8 = (k & 63) * 8;
    row = 8448 + (k >> 6);
  }
  *(short8*)(gp + row * 512 + c8) = (short8){0, 0, 0, 0, 0, 0, 0, 0};
}

__global__ void bn_stats(float* stats, const float* __restrict__ bn_g, const float* __restrict__ bn_b)
{
  const int c = blockIdx.x * 256 + threadIdx.x;
  if (c < 512) {
    float mean = stats[c] * (1.f / 8192.f);
    float var = stats[512 + c] * (1.f / 8192.f) - mean * mean;
    float sc = bn_g[c] * rsqrtf(var + 1e-5f);
    stats[1024 + c] = sc;
    stats[1536 + c] = bn_b[c] - mean * sc;
  }
}

__global__ __launch_bounds__(256) void bn_silu(const short* __restrict__ z, const float* __restrict__ stats,
                                               short* __restrict__ out)
{
  const long base = ((long)blockIdx.x * 256 + threadIdx.x) * 8;
  const int c0 = (int)(base & 511);
  short8 v = *(const short8*)(z + base);
  short8 o;
#pragma unroll
  for (int j = 0; j < 8; ++j) {
    const int c = c0 + j;
    float y = bfs2f(v[j]) * stats[1024 + c] + stats[1536 + c];
    o[j] = f2bfs(y * sigmoidf_(y));
  }
  *(short8*)(out + base) = o;
}

// ---------------------------------------------------------------------------
extern "C" void kernel_launch(void* const* d_in, const int* in_sizes, int n_in,
                              void* d_out, int out_size, void* d_ws, size_t ws_size,
                              hipStream_t stream)
{
  (void)in_sizes; (void)n_in; (void)out_size; (void)ws_size;
  const float* x_in   = (const float*)d_in[0];
  const float* ff1_g  = (const float*)d_in[1];
  const float* ff1_bb = (const float*)d_in[2];
  const float* ff1_w1 = (const float*)d_in[3];
  const float* ff1_b1 = (const float*)d_in[4];
  const float* ff1_w2 = (const float*)d_in[5];
  const float* ff1_b2 = (const float*)d_in[6];
  const float* mha_g  = (const float*)d_in[7];
  const float* mha_b  = (const float*)d_in[8];
  const float* wq     = (const float*)d_in[9];
  const float* bq     = (const float*)d_in[10];
  const float* wk     = (const float*)d_in[11];
  const float* bk     = (const float*)d_in[12];
  const float* wv     = (const float*)d_in[13];
  const float* bv     = (const float*)d_in[14];
  const float* wo     = (const float*)d_in[15];
  const float* bo     = (const float*)d_in[16];
  const float* cv_g   = (const float*)d_in[17];
  const float* cv_b   = (const float*)d_in[18];
  const float* cv_w1  = (const float*)d_in[19];
  const float* cv_b1  = (const float*)d_in[20];
  const float* cv_wd  = (const float*)d_in[21];
  const float* bn_g   = (const float*)d_in[22];
  const float* bn_b   = (const float*)d_in[23];
  const float* cv_w2  = (const float*)d_in[24];
  const float* cv_b2  = (const float*)d_in[25];
  const float* ff2_g  = (const float*)d_in[26];
  const float* ff2_b  = (const float*)d_in[27];
  const float* ff2_w1 = (const float*)d_in[28];
  const float* ff2_b1 = (const float*)d_in[29];
  const float* ff2_w2 = (const float*)d_in[30];
  const float* ff2_b2 = (const float*)d_in[31];
  const float* fin_g  = (const float*)d_in[32];
  const float* fin_b  = (const float*)d_in[33];

  size_t off = 0;
  char* wsb = (char*)d_ws;
  auto take = [&](size_t n) { char* p = wsb + off; off += (n + 255) & ~(size_t)255; return p; };
  short* ff1w1P = (short*)take(2048L * 512 * 2);
  short* ff1w2P = (short*)take(2048L * 512 * 2);
  short* qkvP   = (short*)take(1536L * 512 * 2);
  short* woP    = (short*)take(512L * 512 * 2);
  short* cw1P   = (short*)take(1024L * 512 * 2);
  short* cw2P   = (short*)take(512L * 512 * 2);
  short* wdP    = (short*)take(32L * 512 * 512 * 2);
  short* ff2w1P = (short*)take(2048L * 512 * 2);
  short* ff2w2P = (short*)take(2048L * 512 * 2);
  float* xcur   = (float*)take(8192L * 512 * 4);
  char*  Ra     = take(8192L * 2048 * 2);
  short* Rb     = (short*)take(8192L * 512 * 2);
  short* Rg     = (short*)take((8L * 1056 + 2) * 512 * 2);
  short* parts  = (short*)take(2L * 8192 * 512 * 2);
  short* vt     = (short*)take(64L * 64 * 1024 * 2);
  float* pe     = (float*)take(1024L * 512 * 4);
  float* stats  = (float*)take(2048L * 4);

  short* hid = (short*)Ra;
  short* qkv = (short*)Ra;
  short* y1  = (short*)Ra;

  // ---- one-shot prologue: all packs + pe + stats zero ----
  pack_all<<<25601, 256, 0, stream>>>(
      ff1_w1, ff1_w2, wq, wk, wv, wo, cv_w1, cv_w2, ff2_w1, ff2_w2, cv_wd,
      ff1w1P, ff1w2P, qkvP, woP, cw1P, cw2P, ff2w1P, ff2w2P, wdP, pe, stats);

  // ---- FF1: x1 = 1.5 x + 0.5 (silu(ln(x) W1 + b1) W2 + b2) ----
  ln_rows<0, 0><<<2048, 256, 0, stream>>>(x_in, ff1_g, ff1_bb, nullptr, Rb);
  gemm_bdw<16, EPI_SILU><<<dim3(64, 16), 256, 0, stream>>>(
      Rb, ff1w1P, ff1_b1, nullptr, nullptr, hid);
  gemm_bd<64><<<512, 256, 0, stream>>>(hid, ff1w2P, ff1_b2, x_in, xcur, 1.5f, 0.5f);

  // ---- MHSA: x2 = 2 x1 + (scramble(attn) Wo + bo) ----
  ln_rows<1, 0><<<2048, 256, 0, stream>>>(xcur, mha_g, mha_b, pe, Rb);
  gemm_bdw<12, EPI_QKV><<<dim3(64, 12), 256, 0, stream>>>(
      Rb, qkvP, bq, bk, bv, qkv);
  transpose64b<<<dim3(16, 1, 64), 256, 0, stream>>>(qkv + 1024, 1536, vt, 1024, 3,
                                                    1024L * 1536, 64, 65536);
  flash_attn<<<1024, 256, 0, stream>>>(qkv, vt, Rb);
  gemm_bd<16><<<512, 256, 0, stream>>>(Rb, woP, bo, xcur, xcur, 2.f, 1.f);

  // ---- Conv module ----
  ln_rows<0, 0><<<2048, 256, 0, stream>>>(xcur, cv_g, cv_b, nullptr, Rb);
  gemm_bdw<8, EPI_BBIAS><<<dim3(64, 8), 256, 0, stream>>>(
      Rb, cw1P, cv_b1, nullptr, nullptr, y1);
  glu_fused<<<4161, 256, 0, stream>>>(y1, Rg);
  conv_tap<<<512, 256, 0, stream>>>(Rg, wdP, parts);
  reduce_bn<<<512, 256, 0, stream>>>(parts, 8192L * 512, Rb, stats);
  bn_stats<<<2, 256, 0, stream>>>(stats, bn_g, bn_b);
  bn_silu<<<2048, 256, 0, stream>>>(Rb, stats, (short*)Rg);
  gemm_bd<16><<<512, 256, 0, stream>>>((short*)Rg, cw2P, cv_b2, xcur, xcur, 2.f, 1.f);

  // ---- FF2 ----
  ln_rows<0, 0><<<2048, 256, 0, stream>>>(xcur, ff2_g, ff2_b, nullptr, Rb);
  gemm_bdw<16, EPI_SILU><<<dim3(64, 16), 256, 0, stream>>>(
      Rb, ff2w1P, ff2_b1, nullptr, nullptr, hid);
  gemm_bd<64><<<512, 256, 0, stream>>>(hid, ff2w2P, ff2_b2, xcur, xcur, 1.5f, 0.5f);

  // ---- final LN -> d_out (fp32) ----
  ln_rows<0, 1><<<2048, 256, 0, stream>>>(xcur, fin_g, fin_b, nullptr, (float*)d_out);
}

// Round 25
// 463.196 us; speedup vs baseline: 1.0134x; 1.0134x over previous
//
#include <hip/hip_runtime.h>

// ---------------------------------------------------------------------------
// Conformer block, MI355X gfx950. Inputs/outputs fp32; internal activations
// bf16 with fp32 accumulation via bf16 MFMA 16x16x32.
// Round 25: conv_tap wave re-shape FM=8/FN=2 (wave = 128 rows x 32 cols).
// Kills the 2x duplicated B-fragment loads (waves with equal wn loaded
// identical streams): B wave-loads per block-kk 16 -> 8, B reuse per load
// 4 -> 8 MFMA. LDS reads 4 -> 8/wave-kk (LDS was only 24% busy). Same
// accumulation order per output element -> bitwise-identical. Rest frozen.
// ---------------------------------------------------------------------------

typedef __attribute__((ext_vector_type(4))) float f32x4;
typedef __attribute__((ext_vector_type(8))) short short8;
typedef __attribute__((ext_vector_type(4))) short s16x4;

__device__ __forceinline__ float bfs2f(short s) {
  unsigned u = ((unsigned)(unsigned short)s) << 16;
  float f; __builtin_memcpy(&f, &u, 4); return f;
}
__device__ __forceinline__ short f2bfs(float f) {
  unsigned u; __builtin_memcpy(&u, &f, 4);
  u = (u + 0x7FFFu + ((u >> 16) & 1u)) >> 16;   // RNE
  return (short)u;
}
__device__ __forceinline__ float sigmoidf_(float x) { return 1.f / (1.f + __expf(-x)); }

#define GLOADLDS(gsrc, ldst) \
  __builtin_amdgcn_global_load_lds((__attribute__((address_space(1))) void*)(gsrc), \
                                   (__attribute__((address_space(3))) void*)(ldst), 16, 0, 0)

#define VMCNT_ASM(n) asm volatile("s_waitcnt vmcnt(" #n ")" ::: "memory")
template<int N> __device__ __forceinline__ void vmcnt_wait() {
  if      constexpr (N == 0)  VMCNT_ASM(0);
  else if constexpr (N == 2)  VMCNT_ASM(2);
  else if constexpr (N == 3)  VMCNT_ASM(3);
  else if constexpr (N == 4)  VMCNT_ASM(4);
  else if constexpr (N == 5)  VMCNT_ASM(5);
  else if constexpr (N == 6)  VMCNT_ASM(6);
  else if constexpr (N == 8)  VMCNT_ASM(8);
  else if constexpr (N == 12) VMCNT_ASM(12);
  else                        VMCNT_ASM(0);
}
#define MEMFENCE asm volatile("" ::: "memory")

enum { EPI_SILU = 0, EPI_BBIAS = 1, EPI_QKV = 3 };

// ---------------------------------------------------------------------------
// B-direct wide GEMM (round 24, frozen): C[8192][NB*128] = f(A.B^T + bias).
// ---------------------------------------------------------------------------
template<int NB, int EPI>
__global__ __launch_bounds__(256) void gemm_bdw(
    const short* __restrict__ A,
    const short* __restrict__ wBP,
    const float* __restrict__ bias,
    const float* __restrict__ bias2,
    const float* __restrict__ bias3,
    short* __restrict__ C)
{
  constexpr int NT = 16;
  constexpr int LDC = NB * 128;
  __shared__ short sA[3][128 * 32];
  const int tid = threadIdx.x;
  const int m0 = (int)blockIdx.x * 128, n0 = (int)blockIdx.y * 128;
  const int lane = tid & 63, wid = tid >> 6;
  const int wm = wid >> 1, wn = wid & 1;
  const int lr = lane & 15, kgr = lane >> 4;
  const int aRow = wm * 64, bRow = wn * 64;
  const int aCol = (kgr ^ ((lr >> 1) & 3)) * 8;   // swizzled read granule
  const long NSTR = (long)NT * 512;
  const short* Bp = wBP + (long)((n0 + bRow) >> 4) * NSTR + lane * 8;

  auto stageA = [&](int buf, int t) {
#pragma unroll
    for (int it = 0; it < 2; ++it) {
      int idx = it * 256 + tid;
      int row = idx >> 2;
      int csrc = (idx & 3) ^ ((row >> 1) & 3);    // pre-swizzled source chunk
      GLOADLDS(A + (long)(m0 + row) * 512 + t * 32 + csrc * 8, &sA[buf][idx * 8]);
    }
  };

  f32x4 acc[4][4];
#pragma unroll
  for (int i = 0; i < 4; ++i) {
#pragma unroll
    for (int j = 0; j < 4; ++j) acc[i][j] = (f32x4){0.f, 0.f, 0.f, 0.f};
  }
  short8 b0[4], b1[4];

  stageA(0, 0);
  stageA(1, 1);
  MEMFENCE;
#pragma unroll
  for (int ni = 0; ni < 4; ++ni)
    b0[ni] = *(const short8*)(Bp + ni * NSTR);
  MEMFENCE;
  vmcnt_wait<6>();
  __builtin_amdgcn_s_barrier();

  int rd = 0;
  for (int t = 0; t < NT; t += 2) {
    {
      int wr = rd - 1; if (wr < 0) wr += 3;
      if (t + 2 < NT) stageA(wr, t + 2);
      MEMFENCE;
#pragma unroll
      for (int ni = 0; ni < 4; ++ni)
        b1[ni] = *(const short8*)(Bp + (long)(t + 1) * 512 + ni * NSTR);
      MEMFENCE;
      short8 af[4];
#pragma unroll
      for (int mi = 0; mi < 4; ++mi)
        af[mi] = *(const short8*)&sA[rd][(aRow + mi * 16 + lr) * 32 + aCol];
      __builtin_amdgcn_s_setprio(1);
#pragma unroll
      for (int mi = 0; mi < 4; ++mi) {
#pragma unroll
        for (int ni = 0; ni < 4; ++ni)
          acc[mi][ni] = __builtin_amdgcn_mfma_f32_16x16x32_bf16(af[mi], b0[ni], acc[mi][ni], 0, 0, 0);
      }
      __builtin_amdgcn_s_setprio(0);
      if (t + 2 < NT) vmcnt_wait<6>(); else vmcnt_wait<4>();
      __builtin_amdgcn_s_barrier();
      rd = (rd == 2) ? 0 : rd + 1;
    }
    {
      int wr = rd - 1; if (wr < 0) wr += 3;
      if (t + 3 < NT) stageA(wr, t + 3);
      MEMFENCE;
      if (t + 2 < NT) {
#pragma unroll
        for (int ni = 0; ni < 4; ++ni)
          b0[ni] = *(const short8*)(Bp + (long)(t + 2) * 512 + ni * NSTR);
      }
      MEMFENCE;
      short8 af[4];
#pragma unroll
      for (int mi = 0; mi < 4; ++mi)
        af[mi] = *(const short8*)&sA[rd][(aRow + mi * 16 + lr) * 32 + aCol];
      __builtin_amdgcn_s_setprio(1);
#pragma unroll
      for (int mi = 0; mi < 4; ++mi) {
#pragma unroll
        for (int ni = 0; ni < 4; ++ni)
          acc[mi][ni] = __builtin_amdgcn_mfma_f32_16x16x32_bf16(af[mi], b1[ni], acc[mi][ni], 0, 0, 0);
      }
      __builtin_amdgcn_s_setprio(0);
      if (t + 3 < NT) vmcnt_wait<6>(); else vmcnt_wait<0>();
      __builtin_amdgcn_s_barrier();
      rd = (rd == 2) ? 0 : rd + 1;
    }
  }

  const int baseRow = m0 + aRow, baseCol = n0 + bRow;
#pragma unroll
  for (int mi = 0; mi < 4; ++mi) {
#pragma unroll
    for (int ni = 0; ni < 4; ++ni) {
      const int col = baseCol + ni * 16 + lr;
#pragma unroll
      for (int r = 0; r < 4; ++r) {
        const int row = baseRow + mi * 16 + kgr * 4 + r;
        float v = acc[mi][ni][r];
        if (EPI == EPI_SILU) {
          v += bias[col];
          v = v * sigmoidf_(v);
          C[(long)row * LDC + col] = f2bfs(v);
        } else if (EPI == EPI_BBIAS) {
          v += bias[col];
          C[(long)row * LDC + col] = f2bfs(v);
        } else if (EPI == EPI_QKV) {
          if (col < 512)       v = (v + bias[col]) * 0.125f;
          else if (col < 1024) v += bias2[col - 512];
          else                 v += bias3[col - 1024];
          C[(long)row * LDC + col] = f2bfs(v);
        }
      }
    }
  }
}

// ---------------------------------------------------------------------------
// B-direct GEMM for N=512 residual outputs (round 24, frozen).
// ---------------------------------------------------------------------------
template<int NT>
__global__ __launch_bounds__(256) void gemm_bd(
    const short* __restrict__ A,
    const short* __restrict__ wBP,
    const float* __restrict__ bias,
    const float* __restrict__ resid,
    float* __restrict__ C,
    float alpha, float beta)
{
  constexpr int K = NT * 32;
  __shared__ short sA[3][64 * 32];
  const int tid = threadIdx.x;
  const int x = (int)blockIdx.x >> 2, y = (int)blockIdx.x & 3;
  const int m0 = x * 64, n0 = y * 128;
  const int lane = tid & 63, wid = tid >> 6;
  const int wm = wid >> 1, wn = wid & 1;
  const int lr = lane & 15, kgr = lane >> 4;
  const int aRow = wm * 32, bRow = wn * 64;
  const int aCol = (kgr ^ ((lr >> 1) & 3)) * 8;   // swizzled read granule
  const long NSTR = (long)NT * 512;
  const short* Bp = wBP + (long)((n0 + bRow) >> 4) * NSTR + lane * 8;

  auto stageA = [&](int buf, int t) {
    int row = tid >> 2;
    int csrc = (tid & 3) ^ ((row >> 1) & 3);
    GLOADLDS(A + (long)(m0 + row) * K + t * 32 + csrc * 8, &sA[buf][tid * 8]);
  };

  f32x4 acc[2][4];
#pragma unroll
  for (int i = 0; i < 2; ++i) {
#pragma unroll
    for (int j = 0; j < 4; ++j) acc[i][j] = (f32x4){0.f, 0.f, 0.f, 0.f};
  }
  short8 b0[4], b1[4];

  stageA(0, 0);
  stageA(1, 1);
  MEMFENCE;
#pragma unroll
  for (int ni = 0; ni < 4; ++ni)
    b0[ni] = *(const short8*)(Bp + ni * NSTR);
  MEMFENCE;
  vmcnt_wait<5>();
  __builtin_amdgcn_s_barrier();

  int rd = 0;
  for (int t = 0; t < NT; t += 2) {
    {
      int wr = rd - 1; if (wr < 0) wr += 3;
      if (t + 2 < NT) stageA(wr, t + 2);
      MEMFENCE;
#pragma unroll
      for (int ni = 0; ni < 4; ++ni)
        b1[ni] = *(const short8*)(Bp + (long)(t + 1) * 512 + ni * NSTR);
      MEMFENCE;
      short8 af[2];
#pragma unroll
      for (int mi = 0; mi < 2; ++mi)
        af[mi] = *(const short8*)&sA[rd][(aRow + mi * 16 + lr) * 32 + aCol];
      __builtin_amdgcn_s_setprio(1);
#pragma unroll
      for (int mi = 0; mi < 2; ++mi) {
#pragma unroll
        for (int ni = 0; ni < 4; ++ni)
          acc[mi][ni] = __builtin_amdgcn_mfma_f32_16x16x32_bf16(af[mi], b0[ni], acc[mi][ni], 0, 0, 0);
      }
      __builtin_amdgcn_s_setprio(0);
      if (t + 2 < NT) vmcnt_wait<5>(); else vmcnt_wait<4>();
      __builtin_amdgcn_s_barrier();
      rd = (rd == 2) ? 0 : rd + 1;
    }
    {
      int wr = rd - 1; if (wr < 0) wr += 3;
      if (t + 3 < NT) stageA(wr, t + 3);
      MEMFENCE;
      if (t + 2 < NT) {
#pragma unroll
        for (int ni = 0; ni < 4; ++ni)
          b0[ni] = *(const short8*)(Bp + (long)(t + 2) * 512 + ni * NSTR);
      }
      MEMFENCE;
      short8 af[2];
#pragma unroll
      for (int mi = 0; mi < 2; ++mi)
        af[mi] = *(const short8*)&sA[rd][(aRow + mi * 16 + lr) * 32 + aCol];
      __builtin_amdgcn_s_setprio(1);
#pragma unroll
      for (int mi = 0; mi < 2; ++mi) {
#pragma unroll
        for (int ni = 0; ni < 4; ++ni)
          acc[mi][ni] = __builtin_amdgcn_mfma_f32_16x16x32_bf16(af[mi], b1[ni], acc[mi][ni], 0, 0, 0);
      }
      __builtin_amdgcn_s_setprio(0);
      if (t + 3 < NT) vmcnt_wait<5>(); else vmcnt_wait<0>();
      __builtin_amdgcn_s_barrier();
      rd = (rd == 2) ? 0 : rd + 1;
    }
  }

  const int baseRow = m0 + aRow, baseCol = n0 + bRow;
#pragma unroll
  for (int mi = 0; mi < 2; ++mi) {
#pragma unroll
    for (int ni = 0; ni < 4; ++ni) {
      const int col = baseCol + ni * 16 + lr;
#pragma unroll
      for (int r = 0; r < 4; ++r) {
        const int row = baseRow + mi * 16 + kgr * 4 + r;
        float v = acc[mi][ni][r] + bias[col];
        float rv = resid[(long)row * 512 + col];
        C[(long)row * 512 + col] = alpha * rv + beta * v;
      }
    }
  }
}

// ---------------------------------------------------------------------------
// ONE-SHOT prologue (round 23, frozen).
// ---------------------------------------------------------------------------
__global__ __launch_bounds__(256) void pack_all(
    const float* __restrict__ ff1_w1, const float* __restrict__ ff1_w2,
    const float* __restrict__ wq, const float* __restrict__ wk,
    const float* __restrict__ wv, const float* __restrict__ wo,
    const float* __restrict__ cv_w1, const float* __restrict__ cv_w2,
    const float* __restrict__ ff2_w1, const float* __restrict__ ff2_w2,
    const float* __restrict__ cv_wd,
    short* __restrict__ ff1w1P, short* __restrict__ ff1w2P,
    short* __restrict__ qkvP, short* __restrict__ woP,
    short* __restrict__ cw1P, short* __restrict__ cw2P,
    short* __restrict__ ff2w1P, short* __restrict__ ff2w2P,
    short* __restrict__ wdP, float* __restrict__ pe, float* __restrict__ stats)
{
  int bid = (int)blockIdx.x;
  const int tid = threadIdx.x;

  if (bid < 4096) {
    const int gid = bid * 256 + tid;
    const int n = gid >> 9, k = gid & 511;
    const float v = ff1_w1[((long)k << 11) | n];
    ff1w1P[((long)(n >> 4) * 16 + (k >> 5)) * 512 + ((k >> 3) & 3) * 128 + (n & 15) * 8 + (k & 7)] = f2bfs(v);
    return;
  }
  bid -= 4096;
  if (bid < 4096) {
    const int gid = bid * 256 + tid;
    const int n = gid >> 11, k = gid & 2047;
    const float v = ff1_w2[(long)k * 512 + n];
    ff1w2P[((long)((n >> 4) << 6) + (k >> 5)) * 512 + ((k >> 3) & 3) * 128 + (n & 15) * 8 + (k & 7)] = f2bfs(v);
    return;
  }
  bid -= 4096;
  if (bid < 3072) {
    const int gid = bid * 256 + tid;
    const int n = gid >> 9, k = gid & 511;
    const int sel = n >> 9;
    const int nn = n & 511;
    const float* w = (sel == 0) ? wq : (sel == 1) ? wk : wv;
    const float v = w[(long)(nn >> 6) * 32768 + (long)k * 64 + (nn & 63)];
    qkvP[((long)(n >> 4) * 16 + (k >> 5)) * 512 + ((k >> 3) & 3) * 128 + (n & 15) * 8 + (k & 7)] = f2bfs(v);
    return;
  }
  bid -= 3072;
  if (bid < 1024) {
    const int gid = bid * 256 + tid;
    const int n = gid >> 9, k = gid & 511;
    const float v = wo[(long)k * 512 + n];
    woP[((long)((n >> 4) << 4) + (k >> 5)) * 512 + ((k >> 3) & 3) * 128 + (n & 15) * 8 + (k & 7)] = f2bfs(v);
    return;
  }
  bid -= 1024;
  if (bid < 2048) {
    const int gid = bid * 256 + tid;
    const int n = gid >> 9, k = gid & 511;
    const float v = cv_w1[((long)n << 9) | k];
    cw1P[((long)(n >> 4) * 16 + (k >> 5)) * 512 + ((k >> 3) & 3) * 128 + (n & 15) * 8 + (k & 7)] = f2bfs(v);
    return;
  }
  bid -= 2048;
  if (bid < 1024) {
    const int gid = bid * 256 + tid;
    const int n = gid >> 9, k = gid & 511;
    const float v = cv_w2[((long)n << 9) | k];
    cw2P[((long)((n >> 4) << 4) + (k >> 5)) * 512 + ((k >> 3) & 3) * 128 + (n & 15) * 8 + (k & 7)] = f2bfs(v);
    return;
  }
  bid -= 1024;
  if (bid < 4096) {
    const int gid = bid * 256 + tid;
    const int n = gid >> 9, k = gid & 511;
    const float v = ff2_w1[((long)k << 11) | n];
    ff2w1P[((long)(n >> 4) * 16 + (k >> 5)) * 512 + ((k >> 3) & 3) * 128 + (n & 15) * 8 + (k & 7)] = f2bfs(v);
    return;
  }
  bid -= 4096;
  if (bid < 4096) {
    const int gid = bid * 256 + tid;
    const int n = gid >> 11, k = gid & 2047;
    const float v = ff2_w2[(long)k * 512 + n];
    ff2w2P[((long)((n >> 4) << 6) + (k >> 5)) * 512 + ((k >> 3) & 3) * 128 + (n & 15) * 8 + (k & 7)] = f2bfs(v);
    return;
  }
  bid -= 4096;
  if (bid < 1024) {
    const int gid = bid * 256 + tid;
    const int e = gid >> 9, i = gid & 511;
    const float* src = cv_wd + ((long)e * 512 + i) * 31;
    const long rowtile = (long)(e >> 4) * (512L * 512);
    const int inner = ((i >> 3) & 3) * 128 + (e & 15) * 8 + (i & 7);
#pragma unroll
    for (int KK = 0; KK < 31; ++KK)
      wdP[rowtile + (long)(KK * 16 + (i >> 5)) * 512 + inner] = f2bfs(src[KK]);
    wdP[rowtile + (long)(31 * 16 + (i >> 5)) * 512 + inner] = 0;
    return;
  }
  bid -= 1024;
  if (bid < 1024) {
    const int gid = bid * 256 + tid;
    const int t = gid >> 8, p = gid & 255;
    const float freq = __expf(-(float)p * (9.210340371976184f / 256.f));
    const float ang = (float)t * freq;
    pe[(long)t * 512 + 2 * p]     = sinf(ang);
    pe[(long)t * 512 + 2 * p + 1] = cosf(ang);
    return;
  }
  *(f32x4*)&stats[tid * 4] = (f32x4){0.f, 0.f, 0.f, 0.f};
}

// ---------------------------------------------------------------------------
// Conv, tap-tiled, B-prefetch depth 3; FM=8/FN=2 waves (128 rows x 32 cols
// each). Each wave loads only its own 2 B-frags (no duplication); each frag
// feeds 8 MFMA. LDS A swizzled (kk-dependent read granule).
// ---------------------------------------------------------------------------
__global__ __launch_bounds__(256) void conv_tap(
    const short* __restrict__ glu,
    const short* __restrict__ wdP,
    short* __restrict__ parts)
{
  __shared__ short sA[2][144 * 32];
  const int tid = threadIdx.x;
  const int bid = blockIdx.x;
  const int cc = bid & 7, j = bid >> 3;
  const int y = cc >> 1, kg = cc & 1;
  const int x = j & 7, b = j >> 3;
  const int m0 = x * 128, n0 = y * 128;
  const short* Arow0 = glu + ((long)b * 1056 + m0 + 1 + kg * 16) * 512;
  short* cbase = parts + (long)kg * (8192L * 512) + (long)b * (1024L * 512);

  const int lane = tid & 63, wid = tid >> 6;
  const int lr = lane & 15, kgr = lane >> 4;
  const int bCol = wid * 32;                     // wave's 32-col strip

  const short* Bp = wdP + (long)((n0 + bCol) >> 4) * (512L * 512)
                  + (long)(kg * 256) * 512 + lane * 8;
  const long NSTR = 512L * 512;

  auto stageA = [&](int buf, int ib) {
#pragma unroll
    for (int it = 0; it < 3; ++it) {
      int idx = it * 256 + tid;
      if (idx < 576) {
        int row = idx >> 2;
        int csrc = (idx & 3) ^ ((row >> 1) & 3);   // pre-swizzled source chunk
        GLOADLDS(Arow0 + (long)row * 512 + ib * 32 + csrc * 8,
                 &sA[buf][idx * 8]);
      }
    }
  };

  f32x4 acc[8][2];
#pragma unroll
  for (int i = 0; i < 8; ++i) {
#pragma unroll
    for (int jj = 0; jj < 2; ++jj) acc[i][jj] = (f32x4){0.f, 0.f, 0.f, 0.f};
  }
  short8 bfr[4][2];

#define LOADB(slot_, s_)                                                     \
  {                                                                          \
    const int s2 = (s_);                                                     \
    const long noff = (long)(((s2 & 15) * 16 + (s2 >> 4))) * 512;            \
    _Pragma("unroll")                                                        \
    for (int ni = 0; ni < 2; ++ni)                                           \
      bfr[slot_][ni] = *(const short8*)(Bp + noff + ni * NSTR);              \
  }

  stageA(0, 0);
  MEMFENCE;
  LOADB(0, 0); LOADB(1, 1); LOADB(2, 2);
  MEMFENCE;
  vmcnt_wait<6>();              // stageA(0) done; 3 B prefetch pairs in flight
  __builtin_amdgcn_s_barrier();

  int cur = 0;
  for (int ib = 0; ib < 16; ++ib) {
    if (ib + 1 < 16) stageA(cur ^ 1, ib + 1);
    MEMFENCE;
#pragma unroll
    for (int kk = 0; kk < 16; ++kk) {
      const int s = ib * 16 + kk;
      LOADB((kk + 3) & 3, s + 3);
      MEMFENCE;
      // row = kk + mi*16 + lr; bits 1..2 depend only on (kk+lr)
      const int aColk = (kgr ^ (((kk + lr) >> 1) & 3)) * 8;
      short8 af[8];
#pragma unroll
      for (int mi = 0; mi < 8; ++mi)
        af[mi] = *(const short8*)&sA[cur][(kk + mi * 16 + lr) * 32 + aColk];
      __builtin_amdgcn_s_setprio(1);
#pragma unroll
      for (int mi = 0; mi < 8; ++mi) {
#pragma unroll
        for (int ni = 0; ni < 2; ++ni)
          acc[mi][ni] = __builtin_amdgcn_mfma_f32_16x16x32_bf16(af[mi], bfr[kk & 3][ni], acc[mi][ni], 0, 0, 0);
      }
      __builtin_amdgcn_s_setprio(0);
    }
    vmcnt_wait<6>();            // 3 newest B prefetch pairs in flight
    __builtin_amdgcn_s_barrier();
    cur ^= 1;
  }
  vmcnt_wait<0>();
#undef LOADB

  const int baseCol = n0 + bCol;
#pragma unroll
  for (int mi = 0; mi < 8; ++mi) {
#pragma unroll
    for (int ni = 0; ni < 2; ++ni) {
      const int col = baseCol + ni * 16 + lr;
#pragma unroll
      for (int r = 0; r < 4; ++r) {
        const int row = m0 + mi * 16 + kgr * 4 + r;
        cbase[(long)row * 512 + col] = f2bfs(acc[mi][ni][r]);
      }
    }
  }
}

// ---------------------------------------------------------------------------
// Flash attention, XCD-pinned flat grid 1024 (round 22, frozen).
// ---------------------------------------------------------------------------
__global__ __launch_bounds__(256) void flash_attn(
    const short* __restrict__ qkv,
    const short* __restrict__ vt,
    short* __restrict__ out)
{
  __shared__ short sQ[64 * 64];
  __shared__ short sK[64 * 64];
  __shared__ short sV[64 * 64];
  __shared__ short sP[4][16 * 64];
  const int tid = threadIdx.x;
  const int lane = tid & 63, w = tid >> 6;
  const int lr = lane & 15, kg = lane >> 4;
  const int bid = (int)blockIdx.x;
  const int xcd = bid & 7, j = bid >> 3;
  const int bhi = j & 7, xq = j >> 3;
  const int bh = bhi * 8 + xcd;
  const int b = bh >> 3, h = bh & 7;
  const int q0 = xq * 64;
  const short* qbase = qkv + (long)b * 1024 * 1536 + h * 64;
  const short* kbase = qbase + 512;
  const short* vtb = vt + (long)bh * 65536;

#pragma unroll
  for (int it = 0; it < 2; ++it) {
    int idx = it * 256 + tid;
    int row = idx >> 3, c = (idx & 7) ^ (row & 7);
    GLOADLDS(qbase + (long)(q0 + row) * 1536 + c * 8, &sQ[idx * 8]);
  }
  __syncthreads();
  short8 bq[2];
#pragma unroll
  for (int ks = 0; ks < 2; ++ks)
    bq[ks] = *(const short8*)&sQ[(w * 16 + lr) * 64 + ((ks * 4 + kg) ^ (lr & 7)) * 8];

  f32x4 po[4];
#pragma unroll
  for (int mi = 0; mi < 4; ++mi) po[mi] = (f32x4){0.f, 0.f, 0.f, 0.f};
  float m = -3.0e38f, l = 0.f;

  for (int s0 = 0; s0 < 1024; s0 += 64) {
#pragma unroll
    for (int it = 0; it < 2; ++it) {
      int idx = it * 256 + tid;
      int row = idx >> 3, c = (idx & 7) ^ (row & 7);
      GLOADLDS(kbase + (long)(s0 + row) * 1536 + c * 8, &sK[idx * 8]);
    }
#pragma unroll
    for (int it = 0; it < 2; ++it) {
      int idx = it * 256 + tid;
      int row = idx >> 3, c = (idx & 7) ^ (row & 7);
      GLOADLDS(vtb + (long)row * 1024 + s0 + c * 8, &sV[idx * 8]);
    }
    __syncthreads();

    f32x4 as[4];
#pragma unroll
    for (int mi = 0; mi < 4; ++mi) as[mi] = (f32x4){0.f, 0.f, 0.f, 0.f};
    __builtin_amdgcn_s_setprio(1);
#pragma unroll
    for (int ks = 0; ks < 2; ++ks) {
#pragma unroll
      for (int mi = 0; mi < 4; ++mi) {
        short8 ak = *(const short8*)&sK[(mi * 16 + lr) * 64 + ((ks * 4 + kg) ^ (lr & 7)) * 8];
        as[mi] = __builtin_amdgcn_mfma_f32_16x16x32_bf16(ak, bq[ks], as[mi], 0, 0, 0);
      }
    }
    __builtin_amdgcn_s_setprio(0);

    float rmax = as[0][0];
#pragma unroll
    for (int mi = 0; mi < 4; ++mi) {
#pragma unroll
      for (int r = 0; r < 4; ++r) rmax = fmaxf(rmax, as[mi][r]);
    }
    rmax = fmaxf(rmax, __shfl_xor(rmax, 16));
    rmax = fmaxf(rmax, __shfl_xor(rmax, 32));
    const float mn = fmaxf(m, rmax);
    const float sc = __expf(m - mn);
    float p[4][4];
    float rsum = 0.f;
#pragma unroll
    for (int mi = 0; mi < 4; ++mi) {
#pragma unroll
      for (int r = 0; r < 4; ++r) { p[mi][r] = __expf(as[mi][r] - mn); rsum += p[mi][r]; }
    }
    rsum += __shfl_xor(rsum, 16);
    rsum += __shfl_xor(rsum, 32);
    l = l * sc + rsum;
    m = mn;
#pragma unroll
    for (int mi = 0; mi < 4; ++mi) {
#pragma unroll
      for (int r = 0; r < 4; ++r) po[mi][r] *= sc;
    }
#pragma unroll
    for (int mi = 0; mi < 4; ++mi) {
      s16x4 pk;
#pragma unroll
      for (int r = 0; r < 4; ++r) pk[r] = f2bfs(p[mi][r]);
      *(s16x4*)&sP[w][lr * 64 + ((mi ^ (lr & 3)) * 16 + kg * 4)] = pk;
    }
    __builtin_amdgcn_s_setprio(1);
#pragma unroll
    for (int ks = 0; ks < 2; ++ks) {
      short8 bp = *(const short8*)&sP[w][lr * 64 + (((ks * 2 + (kg >> 1)) ^ (lr & 3)) * 16 + (kg & 1) * 8)];
#pragma unroll
      for (int mi = 0; mi < 4; ++mi) {
        short8 av = *(const short8*)&sV[(mi * 16 + lr) * 64 + ((ks * 4 + kg) ^ (lr & 7)) * 8];
        po[mi] = __builtin_amdgcn_mfma_f32_16x16x32_bf16(av, bp, po[mi], 0, 0, 0);
      }
    }
    __builtin_amdgcn_s_setprio(0);
    __syncthreads();
  }

  const float inv = 1.f / l;
  const int t2 = q0 + w * 16 + lr;
  const int n = h * 1024 + t2;
  short* ob = out + ((long)b * 1024 + (n >> 3)) * 512 + (n & 7) * 64;
#pragma unroll
  for (int mi = 0; mi < 4; ++mi) {
    s16x4 o;
#pragma unroll
    for (int r = 0; r < 4; ++r) o[r] = f2bfs(po[mi][r] * inv);
    *(s16x4*)&ob[mi * 16 + kg * 4] = o;
  }
}

// ---------------------------------------------------------------------------
__global__ __launch_bounds__(256) void reduce_bn(
    const short* __restrict__ parts, long pstride,
    short* __restrict__ z, float* stats)
{
  const int r0 = blockIdx.x * 16;
  const int c = threadIdx.x * 2;
  float s0 = 0.f, s1 = 0.f, q0 = 0.f, q1 = 0.f;
#pragma unroll 4
  for (int r = 0; r < 16; ++r) {
    const long idx = (long)(r0 + r) * 512 + c;
    int p0 = *(const int*)&parts[idx];
    int p1 = *(const int*)&parts[idx + pstride];
    float a0 = bfs2f((short)(p0 & 0xffff)) + bfs2f((short)(p1 & 0xffff));
    float a1 = bfs2f((short)(p0 >> 16)) + bfs2f((short)(p1 >> 16));
    int zo = ((int)(unsigned short)f2bfs(a0)) | (((int)(unsigned short)f2bfs(a1)) << 16);
    *(int*)&z[idx] = zo;
    s0 += a0; s1 += a1; q0 += a0 * a0; q1 += a1 * a1;
  }
  atomicAdd(&stats[c], s0);
  atomicAdd(&stats[c + 1], s1);
  atomicAdd(&stats[512 + c], q0);
  atomicAdd(&stats[512 + c + 1], q1);
}

// ---------------------------------------------------------------------------
template<int ADDPE, int OUTF32>
__global__ __launch_bounds__(256) void ln_rows(
    const float* __restrict__ X, const float* __restrict__ g, const float* __restrict__ b,
    const float* __restrict__ pe, void* __restrict__ Y)
{
  const int row = blockIdx.x * 4 + (threadIdx.x >> 6);
  const int lane = threadIdx.x & 63;
  const int c0 = lane * 8;
  const float* src = X + (long)row * 512 + c0;
  f32x4 a = *(const f32x4*)src, c = *(const f32x4*)(src + 4);
  float x[8] = {a[0], a[1], a[2], a[3], c[0], c[1], c[2], c[3]};
  float s = 0.f, q = 0.f;
#pragma unroll
  for (int j = 0; j < 8; ++j) { s += x[j]; q += x[j] * x[j]; }
#pragma unroll
  for (int off = 32; off > 0; off >>= 1) { s += __shfl_xor(s, off); q += __shfl_xor(q, off); }
  const float mean = s * (1.f / 512.f);
  const float var = q * (1.f / 512.f) - mean * mean;
  const float rstd = rsqrtf(var + 1e-5f);
  f32x4 g0 = *(const f32x4*)(g + c0), g1 = *(const f32x4*)(g + c0 + 4);
  f32x4 b0 = *(const f32x4*)(b + c0), b1 = *(const f32x4*)(b + c0 + 4);
  float gg[8] = {g0[0], g0[1], g0[2], g0[3], g1[0], g1[1], g1[2], g1[3]};
  float bb[8] = {b0[0], b0[1], b0[2], b0[3], b1[0], b1[1], b1[2], b1[3]};
  float y[8];
#pragma unroll
  for (int j = 0; j < 8; ++j) {
    y[j] = (x[j] - mean) * rstd * gg[j] + bb[j];
    if (ADDPE) y[j] += pe[(long)(row & 1023) * 512 + c0 + j];
  }
  if (OUTF32) {
    float* dst = (float*)Y + (long)row * 512 + c0;
    *(f32x4*)dst = (f32x4){y[0], y[1], y[2], y[3]};
    *(f32x4*)(dst + 4) = (f32x4){y[4], y[5], y[6], y[7]};
  } else {
    short8 o;
#pragma unroll
    for (int j = 0; j < 8; ++j) o[j] = f2bfs(y[j]);
    *(short8*)((short*)Y + (long)row * 512 + c0) = o;
  }
}

// ---------------------------------------------------------------------------
__global__ __launch_bounds__(256) void transpose64b(
    const short* __restrict__ in, int ldin, short* __restrict__ out, int ldout,
    int zshift, long zh_in, long zl_in, long z_out)
{
  __shared__ short t[64][72];
  const int z = blockIdx.z;
  const long inoff = (long)(z >> zshift) * zh_in + (long)(z & ((1 << zshift) - 1)) * zl_in;
  const int tr = blockIdx.x;
  const short* src = in + inoff + (long)(tr * 64) * ldin;
  short* dst = out + (long)z * z_out + tr * 64;
  const int tid = threadIdx.x;
#pragma unroll
  for (int p = 0; p < 2; ++p) {
    int idx = p * 256 + tid;
    int r = idx >> 3, c8 = (idx & 7) * 8;
    short8 v = *(const short8*)(src + (long)r * ldin + c8);
#pragma unroll
    for (int j = 0; j < 8; ++j) t[r][c8 + j] = v[j];
  }
  __syncthreads();
#pragma unroll
  for (int p = 0; p < 2; ++p) {
    int idx = p * 256 + tid;
    int c = idx >> 3, r8 = (idx & 7) * 8;
    short8 v;
#pragma unroll
    for (int j = 0; j < 8; ++j) v[j] = t[r8 + j][c];
    *(short8*)(dst + (long)c * ldout + r8) = v;
  }
}

// ---------------------------------------------------------------------------
// glu + halo zero, fused (round 23, frozen).
// ---------------------------------------------------------------------------
__global__ __launch_bounds__(256) void glu_fused(const short* __restrict__ y1, short* __restrict__ gp)
{
  const int bb = (int)blockIdx.x;
  const int tid = threadIdx.x;
  if (bb < 4096) {
    const int gid = bb * 256 + tid;
    const int row = gid >> 7;
    const int ci = (gid & 127) * 4;
    const short* base = y1 + (long)row * 1024;
    s16x4 a = *(const s16x4*)(base + ci);
    s16x4 g = *(const s16x4*)(base + 512 + ci);
    const int b = row >> 10, t = row & 1023;
    s16x4 o;
#pragma unroll
    for (int j = 0; j < 4; ++j) o[j] = f2bfs(bfs2f(a[j]) * sigmoidf_(bfs2f(g[j])));
    *(s16x4*)(gp + ((long)b * 1056 + 16 + t) * 512 + ci) = o;
    return;
  }
  const int gid = (bb - 4096) * 256 + tid;
  if (gid >= 16512) return;
  long row;
  int c8;
  if (gid < 16384) {
    const int b = gid >> 11;
    const int r = (gid >> 6) & 31;
    c8 = (gid & 63) * 8;
    row = (long)b * 1056 + ((r < 16) ? r : (1024 + r));
  } else {
    const int k = gid - 16384;
    c8 = (k & 63) * 8;
    row = 8448 + (k >> 6);
  }
  *(short8*)(gp + row * 512 + c8) = (short8){0, 0, 0, 0, 0, 0, 0, 0};
}

__global__ void bn_stats(float* stats, const float* __restrict__ bn_g, const float* __restrict__ bn_b)
{
  const int c = blockIdx.x * 256 + threadIdx.x;
  if (c < 512) {
    float mean = stats[c] * (1.f / 8192.f);
    float var = stats[512 + c] * (1.f / 8192.f) - mean * mean;
    float sc = bn_g[c] * rsqrtf(var + 1e-5f);
    stats[1024 + c] = sc;
    stats[1536 + c] = bn_b[c] - mean * sc;
  }
}

__global__ __launch_bounds__(256) void bn_silu(const short* __restrict__ z, const float* __restrict__ stats,
                                               short* __restrict__ out)
{
  const long base = ((long)blockIdx.x * 256 + threadIdx.x) * 8;
  const int c0 = (int)(base & 511);
  short8 v = *(const short8*)(z + base);
  short8 o;
#pragma unroll
  for (int j = 0; j < 8; ++j) {
    const int c = c0 + j;
    float y = bfs2f(v[j]) * stats[1024 + c] + stats[1536 + c];
    o[j] = f2bfs(y * sigmoidf_(y));
  }
  *(short8*)(out + base) = o;
}

// ---------------------------------------------------------------------------
extern "C" void kernel_launch(void* const* d_in, const int* in_sizes, int n_in,
                              void* d_out, int out_size, void* d_ws, size_t ws_size,
                              hipStream_t stream)
{
  (void)in_sizes; (void)n_in; (void)out_size; (void)ws_size;
  const float* x_in   = (const float*)d_in[0];
  const float* ff1_g  = (const float*)d_in[1];
  const float* ff1_bb = (const float*)d_in[2];
  const float* ff1_w1 = (const float*)d_in[3];
  const float* ff1_b1 = (const float*)d_in[4];
  const float* ff1_w2 = (const float*)d_in[5];
  const float* ff1_b2 = (const float*)d_in[6];
  const float* mha_g  = (const float*)d_in[7];
  const float* mha_b  = (const float*)d_in[8];
  const float* wq     = (const float*)d_in[9];
  const float* bq     = (const float*)d_in[10];
  const float* wk     = (const float*)d_in[11];
  const float* bk     = (const float*)d_in[12];
  const float* wv     = (const float*)d_in[13];
  const float* bv     = (const float*)d_in[14];
  const float* wo     = (const float*)d_in[15];
  const float* bo     = (const float*)d_in[16];
  const float* cv_g   = (const float*)d_in[17];
  const float* cv_b   = (const float*)d_in[18];
  const float* cv_w1  = (const float*)d_in[19];
  const float* cv_b1  = (const float*)d_in[20];
  const float* cv_wd  = (const float*)d_in[21];
  const float* bn_g   = (const float*)d_in[22];
  const float* bn_b   = (const float*)d_in[23];
  const float* cv_w2  = (const float*)d_in[24];
  const float* cv_b2  = (const float*)d_in[25];
  const float* ff2_g  = (const float*)d_in[26];
  const float* ff2_b  = (const float*)d_in[27];
  const float* ff2_w1 = (const float*)d_in[28];
  const float* ff2_b1 = (const float*)d_in[29];
  const float* ff2_w2 = (const float*)d_in[30];
  const float* ff2_b2 = (const float*)d_in[31];
  const float* fin_g  = (const float*)d_in[32];
  const float* fin_b  = (const float*)d_in[33];

  size_t off = 0;
  char* wsb = (char*)d_ws;
  auto take = [&](size_t n) { char* p = wsb + off; off += (n + 255) & ~(size_t)255; return p; };
  short* ff1w1P = (short*)take(2048L * 512 * 2);
  short* ff1w2P = (short*)take(2048L * 512 * 2);
  short* qkvP   = (short*)take(1536L * 512 * 2);
  short* woP    = (short*)take(512L * 512 * 2);
  short* cw1P   = (short*)take(1024L * 512 * 2);
  short* cw2P   = (short*)take(512L * 512 * 2);
  short* wdP    = (short*)take(32L * 512 * 512 * 2);
  short* ff2w1P = (short*)take(2048L * 512 * 2);
  short* ff2w2P = (short*)take(2048L * 512 * 2);
  float* xcur   = (float*)take(8192L * 512 * 4);
  char*  Ra     = take(8192L * 2048 * 2);
  short* Rb     = (short*)take(8192L * 512 * 2);
  short* Rg     = (short*)take((8L * 1056 + 2) * 512 * 2);
  short* parts  = (short*)take(2L * 8192 * 512 * 2);
  short* vt     = (short*)take(64L * 64 * 1024 * 2);
  float* pe     = (float*)take(1024L * 512 * 4);
  float* stats  = (float*)take(2048L * 4);

  short* hid = (short*)Ra;
  short* qkv = (short*)Ra;
  short* y1  = (short*)Ra;

  // ---- one-shot prologue: all packs + pe + stats zero ----
  pack_all<<<25601, 256, 0, stream>>>(
      ff1_w1, ff1_w2, wq, wk, wv, wo, cv_w1, cv_w2, ff2_w1, ff2_w2, cv_wd,
      ff1w1P, ff1w2P, qkvP, woP, cw1P, cw2P, ff2w1P, ff2w2P, wdP, pe, stats);

  // ---- FF1: x1 = 1.5 x + 0.5 (silu(ln(x) W1 + b1) W2 + b2) ----
  ln_rows<0, 0><<<2048, 256, 0, stream>>>(x_in, ff1_g, ff1_bb, nullptr, Rb);
  gemm_bdw<16, EPI_SILU><<<dim3(64, 16), 256, 0, stream>>>(
      Rb, ff1w1P, ff1_b1, nullptr, nullptr, hid);
  gemm_bd<64><<<512, 256, 0, stream>>>(hid, ff1w2P, ff1_b2, x_in, xcur, 1.5f, 0.5f);

  // ---- MHSA: x2 = 2 x1 + (scramble(attn) Wo + bo) ----
  ln_rows<1, 0><<<2048, 256, 0, stream>>>(xcur, mha_g, mha_b, pe, Rb);
  gemm_bdw<12, EPI_QKV><<<dim3(64, 12), 256, 0, stream>>>(
      Rb, qkvP, bq, bk, bv, qkv);
  transpose64b<<<dim3(16, 1, 64), 256, 0, stream>>>(qkv + 1024, 1536, vt, 1024, 3,
                                                    1024L * 1536, 64, 65536);
  flash_attn<<<1024, 256, 0, stream>>>(qkv, vt, Rb);
  gemm_bd<16><<<512, 256, 0, stream>>>(Rb, woP, bo, xcur, xcur, 2.f, 1.f);

  // ---- Conv module ----
  ln_rows<0, 0><<<2048, 256, 0, stream>>>(xcur, cv_g, cv_b, nullptr, Rb);
  gemm_bdw<8, EPI_BBIAS><<<dim3(64, 8), 256, 0, stream>>>(
      Rb, cw1P, cv_b1, nullptr, nullptr, y1);
  glu_fused<<<4161, 256, 0, stream>>>(y1, Rg);
  conv_tap<<<512, 256, 0, stream>>>(Rg, wdP, parts);
  reduce_bn<<<512, 256, 0, stream>>>(parts, 8192L * 512, Rb, stats);
  bn_stats<<<2, 256, 0, stream>>>(stats, bn_g, bn_b);
  bn_silu<<<2048, 256, 0, stream>>>(Rb, stats, (short*)Rg);
  gemm_bd<16><<<512, 256, 0, stream>>>((short*)Rg, cw2P, cv_b2, xcur, xcur, 2.f, 1.f);

  // ---- FF2 ----
  ln_rows<0, 0><<<2048, 256, 0, stream>>>(xcur, ff2_g, ff2_b, nullptr, Rb);
  gemm_bdw<16, EPI_SILU><<<dim3(64, 16), 256, 0, stream>>>(
      Rb, ff2w1P, ff2_b1, nullptr, nullptr, hid);
  gemm_bd<64><<<512, 256, 0, stream>>>(hid, ff2w2P, ff2_b2, xcur, xcur, 1.5f, 0.5f);

  // ---- final LN -> d_out (fp32) ----
  ln_rows<0, 1><<<2048, 256, 0, stream>>>(xcur, fin_g, fin_b, nullptr, (float*)d_out);
}

// Round 26
// 440.073 us; speedup vs baseline: 1.0667x; 1.0525x over previous
//
#include <hip/hip_runtime.h>

// ---------------------------------------------------------------------------
// Conformer block, MI355X gfx950. Inputs/outputs fp32; internal activations
// bf16 with fp32 accumulation via bf16 MFMA 16x16x32.
// Round 26: FM=8/FN=2 wave re-shape (proven +7us on conv in r25) ported to
// gemm_bdw (waves 2x2 -> 1x4, 128rows x 32cols each) and gemm_bd (-> 64x32).
// Kills 2x duplicated B-fragment wave-loads; B reuse per load doubles.
// vmcnt rescaled (B pairs are 2 loads). Per-output k-sequence unchanged ->
// bitwise-identical. conv_tap (r25) and all else frozen.
// ---------------------------------------------------------------------------

typedef __attribute__((ext_vector_type(4))) float f32x4;
typedef __attribute__((ext_vector_type(8))) short short8;
typedef __attribute__((ext_vector_type(4))) short s16x4;

__device__ __forceinline__ float bfs2f(short s) {
  unsigned u = ((unsigned)(unsigned short)s) << 16;
  float f; __builtin_memcpy(&f, &u, 4); return f;
}
__device__ __forceinline__ short f2bfs(float f) {
  unsigned u; __builtin_memcpy(&u, &f, 4);
  u = (u + 0x7FFFu + ((u >> 16) & 1u)) >> 16;   // RNE
  return (short)u;
}
__device__ __forceinline__ float sigmoidf_(float x) { return 1.f / (1.f + __expf(-x)); }

#define GLOADLDS(gsrc, ldst) \
  __builtin_amdgcn_global_load_lds((__attribute__((address_space(1))) void*)(gsrc), \
                                   (__attribute__((address_space(3))) void*)(ldst), 16, 0, 0)

#define VMCNT_ASM(n) asm volatile("s_waitcnt vmcnt(" #n ")" ::: "memory")
template<int N> __device__ __forceinline__ void vmcnt_wait() {
  if      constexpr (N == 0)  VMCNT_ASM(0);
  else if constexpr (N == 2)  VMCNT_ASM(2);
  else if constexpr (N == 3)  VMCNT_ASM(3);
  else if constexpr (N == 4)  VMCNT_ASM(4);
  else if constexpr (N == 5)  VMCNT_ASM(5);
  else if constexpr (N == 6)  VMCNT_ASM(6);
  else if constexpr (N == 8)  VMCNT_ASM(8);
  else if constexpr (N == 12) VMCNT_ASM(12);
  else                        VMCNT_ASM(0);
}
#define MEMFENCE asm volatile("" ::: "memory")

enum { EPI_SILU = 0, EPI_BBIAS = 1, EPI_QKV = 3 };

// ---------------------------------------------------------------------------
// B-direct wide GEMM: C[8192][NB*128] = f(A.B^T + bias). 1x4 waves: each
// wave owns 128 rows x 32 cols; loads only its own 2 B-frags per k-step.
// ---------------------------------------------------------------------------
template<int NB, int EPI>
__global__ __launch_bounds__(256) void gemm_bdw(
    const short* __restrict__ A,
    const short* __restrict__ wBP,
    const float* __restrict__ bias,
    const float* __restrict__ bias2,
    const float* __restrict__ bias3,
    short* __restrict__ C)
{
  constexpr int NT = 16;
  constexpr int LDC = NB * 128;
  __shared__ short sA[3][128 * 32];
  const int tid = threadIdx.x;
  const int m0 = (int)blockIdx.x * 128, n0 = (int)blockIdx.y * 128;
  const int lane = tid & 63, wid = tid >> 6;
  const int lr = lane & 15, kgr = lane >> 4;
  const int bCol = wid * 32;                      // wave's 32-col strip
  const int aCol = (kgr ^ ((lr >> 1) & 3)) * 8;   // swizzled read granule
  const long NSTR = (long)NT * 512;
  const short* Bp = wBP + (long)((n0 + bCol) >> 4) * NSTR + lane * 8;

  auto stageA = [&](int buf, int t) {
#pragma unroll
    for (int it = 0; it < 2; ++it) {
      int idx = it * 256 + tid;
      int row = idx >> 2;
      int csrc = (idx & 3) ^ ((row >> 1) & 3);    // pre-swizzled source chunk
      GLOADLDS(A + (long)(m0 + row) * 512 + t * 32 + csrc * 8, &sA[buf][idx * 8]);
    }
  };

  f32x4 acc[8][2];
#pragma unroll
  for (int i = 0; i < 8; ++i) {
#pragma unroll
    for (int j = 0; j < 2; ++j) acc[i][j] = (f32x4){0.f, 0.f, 0.f, 0.f};
  }
  short8 b0[2], b1[2];

  stageA(0, 0);
  stageA(1, 1);
  MEMFENCE;
#pragma unroll
  for (int ni = 0; ni < 2; ++ni)
    b0[ni] = *(const short8*)(Bp + ni * NSTR);
  MEMFENCE;
  vmcnt_wait<4>();              // stageA(0) done; stageA(1)(2) + b0(2) in flight
  __builtin_amdgcn_s_barrier();

  int rd = 0;
  for (int t = 0; t < NT; t += 2) {
    { // even: consume b0, prefetch B(t+1)->b1, stage A(t+2)
      int wr = rd - 1; if (wr < 0) wr += 3;
      if (t + 2 < NT) stageA(wr, t + 2);
      MEMFENCE;
#pragma unroll
      for (int ni = 0; ni < 2; ++ni)
        b1[ni] = *(const short8*)(Bp + (long)(t + 1) * 512 + ni * NSTR);
      MEMFENCE;
      short8 af[8];
#pragma unroll
      for (int mi = 0; mi < 8; ++mi)
        af[mi] = *(const short8*)&sA[rd][(mi * 16 + lr) * 32 + aCol];
      __builtin_amdgcn_s_setprio(1);
#pragma unroll
      for (int mi = 0; mi < 8; ++mi) {
#pragma unroll
        for (int ni = 0; ni < 2; ++ni)
          acc[mi][ni] = __builtin_amdgcn_mfma_f32_16x16x32_bf16(af[mi], b0[ni], acc[mi][ni], 0, 0, 0);
      }
      __builtin_amdgcn_s_setprio(0);
      if (t + 2 < NT) vmcnt_wait<4>(); else vmcnt_wait<2>();
      __builtin_amdgcn_s_barrier();
      rd = (rd == 2) ? 0 : rd + 1;
    }
    { // odd: consume b1, prefetch B(t+2)->b0, stage A(t+3)
      int wr = rd - 1; if (wr < 0) wr += 3;
      if (t + 3 < NT) stageA(wr, t + 3);
      MEMFENCE;
      if (t + 2 < NT) {
#pragma unroll
        for (int ni = 0; ni < 2; ++ni)
          b0[ni] = *(const short8*)(Bp + (long)(t + 2) * 512 + ni * NSTR);
      }
      MEMFENCE;
      short8 af[8];
#pragma unroll
      for (int mi = 0; mi < 8; ++mi)
        af[mi] = *(const short8*)&sA[rd][(mi * 16 + lr) * 32 + aCol];
      __builtin_amdgcn_s_setprio(1);
#pragma unroll
      for (int mi = 0; mi < 8; ++mi) {
#pragma unroll
        for (int ni = 0; ni < 2; ++ni)
          acc[mi][ni] = __builtin_amdgcn_mfma_f32_16x16x32_bf16(af[mi], b1[ni], acc[mi][ni], 0, 0, 0);
      }
      __builtin_amdgcn_s_setprio(0);
      if (t + 3 < NT) vmcnt_wait<4>(); else vmcnt_wait<0>();
      __builtin_amdgcn_s_barrier();
      rd = (rd == 2) ? 0 : rd + 1;
    }
  }

  const int baseCol = n0 + bCol;
#pragma unroll
  for (int mi = 0; mi < 8; ++mi) {
#pragma unroll
    for (int ni = 0; ni < 2; ++ni) {
      const int col = baseCol + ni * 16 + lr;
#pragma unroll
      for (int r = 0; r < 4; ++r) {
        const int row = m0 + mi * 16 + kgr * 4 + r;
        float v = acc[mi][ni][r];
        if (EPI == EPI_SILU) {
          v += bias[col];
          v = v * sigmoidf_(v);
          C[(long)row * LDC + col] = f2bfs(v);
        } else if (EPI == EPI_BBIAS) {
          v += bias[col];
          C[(long)row * LDC + col] = f2bfs(v);
        } else if (EPI == EPI_QKV) {
          if (col < 512)       v = (v + bias[col]) * 0.125f;
          else if (col < 1024) v += bias2[col - 512];
          else                 v += bias3[col - 1024];
          C[(long)row * LDC + col] = f2bfs(v);
        }
      }
    }
  }
}

// ---------------------------------------------------------------------------
// B-direct GEMM for N=512 residual outputs. 1x4 waves: 64 rows x 32 cols.
// ---------------------------------------------------------------------------
template<int NT>
__global__ __launch_bounds__(256) void gemm_bd(
    const short* __restrict__ A,
    const short* __restrict__ wBP,
    const float* __restrict__ bias,
    const float* __restrict__ resid,
    float* __restrict__ C,
    float alpha, float beta)
{
  constexpr int K = NT * 32;
  __shared__ short sA[3][64 * 32];
  const int tid = threadIdx.x;
  const int x = (int)blockIdx.x >> 2, y = (int)blockIdx.x & 3;
  const int m0 = x * 64, n0 = y * 128;
  const int lane = tid & 63, wid = tid >> 6;
  const int lr = lane & 15, kgr = lane >> 4;
  const int bCol = wid * 32;                      // wave's 32-col strip
  const int aCol = (kgr ^ ((lr >> 1) & 3)) * 8;   // swizzled read granule
  const long NSTR = (long)NT * 512;
  const short* Bp = wBP + (long)((n0 + bCol) >> 4) * NSTR + lane * 8;

  auto stageA = [&](int buf, int t) {
    int row = tid >> 2;
    int csrc = (tid & 3) ^ ((row >> 1) & 3);
    GLOADLDS(A + (long)(m0 + row) * K + t * 32 + csrc * 8, &sA[buf][tid * 8]);
  };

  f32x4 acc[4][2];
#pragma unroll
  for (int i = 0; i < 4; ++i) {
#pragma unroll
    for (int j = 0; j < 2; ++j) acc[i][j] = (f32x4){0.f, 0.f, 0.f, 0.f};
  }
  short8 b0[2], b1[2];

  stageA(0, 0);
  stageA(1, 1);
  MEMFENCE;
#pragma unroll
  for (int ni = 0; ni < 2; ++ni)
    b0[ni] = *(const short8*)(Bp + ni * NSTR);
  MEMFENCE;
  vmcnt_wait<3>();              // stageA(0) done; stageA(1)(1) + b0(2) in flight
  __builtin_amdgcn_s_barrier();

  int rd = 0;
  for (int t = 0; t < NT; t += 2) {
    {
      int wr = rd - 1; if (wr < 0) wr += 3;
      if (t + 2 < NT) stageA(wr, t + 2);
      MEMFENCE;
#pragma unroll
      for (int ni = 0; ni < 2; ++ni)
        b1[ni] = *(const short8*)(Bp + (long)(t + 1) * 512 + ni * NSTR);
      MEMFENCE;
      short8 af[4];
#pragma unroll
      for (int mi = 0; mi < 4; ++mi)
        af[mi] = *(const short8*)&sA[rd][(mi * 16 + lr) * 32 + aCol];
      __builtin_amdgcn_s_setprio(1);
#pragma unroll
      for (int mi = 0; mi < 4; ++mi) {
#pragma unroll
        for (int ni = 0; ni < 2; ++ni)
          acc[mi][ni] = __builtin_amdgcn_mfma_f32_16x16x32_bf16(af[mi], b0[ni], acc[mi][ni], 0, 0, 0);
      }
      __builtin_amdgcn_s_setprio(0);
      if (t + 2 < NT) vmcnt_wait<3>(); else vmcnt_wait<2>();
      __builtin_amdgcn_s_barrier();
      rd = (rd == 2) ? 0 : rd + 1;
    }
    {
      int wr = rd - 1; if (wr < 0) wr += 3;
      if (t + 3 < NT) stageA(wr, t + 3);
      MEMFENCE;
      if (t + 2 < NT) {
#pragma unroll
        for (int ni = 0; ni < 2; ++ni)
          b0[ni] = *(const short8*)(Bp + (long)(t + 2) * 512 + ni * NSTR);
      }
      MEMFENCE;
      short8 af[4];
#pragma unroll
      for (int mi = 0; mi < 4; ++mi)
        af[mi] = *(const short8*)&sA[rd][(mi * 16 + lr) * 32 + aCol];
      __builtin_amdgcn_s_setprio(1);
#pragma unroll
      for (int mi = 0; mi < 4; ++mi) {
#pragma unroll
        for (int ni = 0; ni < 2; ++ni)
          acc[mi][ni] = __builtin_amdgcn_mfma_f32_16x16x32_bf16(af[mi], b1[ni], acc[mi][ni], 0, 0, 0);
      }
      __builtin_amdgcn_s_setprio(0);
      if (t + 3 < NT) vmcnt_wait<3>(); else vmcnt_wait<0>();
      __builtin_amdgcn_s_barrier();
      rd = (rd == 2) ? 0 : rd + 1;
    }
  }

  const int baseCol = n0 + bCol;
#pragma unroll
  for (int mi = 0; mi < 4; ++mi) {
#pragma unroll
    for (int ni = 0; ni < 2; ++ni) {
      const int col = baseCol + ni * 16 + lr;
#pragma unroll
      for (int r = 0; r < 4; ++r) {
        const int row = m0 + mi * 16 + kgr * 4 + r;
        float v = acc[mi][ni][r] + bias[col];
        float rv = resid[(long)row * 512 + col];
        C[(long)row * 512 + col] = alpha * rv + beta * v;
      }
    }
  }
}

// ---------------------------------------------------------------------------
// ONE-SHOT prologue (round 23, frozen).
// ---------------------------------------------------------------------------
__global__ __launch_bounds__(256) void pack_all(
    const float* __restrict__ ff1_w1, const float* __restrict__ ff1_w2,
    const float* __restrict__ wq, const float* __restrict__ wk,
    const float* __restrict__ wv, const float* __restrict__ wo,
    const float* __restrict__ cv_w1, const float* __restrict__ cv_w2,
    const float* __restrict__ ff2_w1, const float* __restrict__ ff2_w2,
    const float* __restrict__ cv_wd,
    short* __restrict__ ff1w1P, short* __restrict__ ff1w2P,
    short* __restrict__ qkvP, short* __restrict__ woP,
    short* __restrict__ cw1P, short* __restrict__ cw2P,
    short* __restrict__ ff2w1P, short* __restrict__ ff2w2P,
    short* __restrict__ wdP, float* __restrict__ pe, float* __restrict__ stats)
{
  int bid = (int)blockIdx.x;
  const int tid = threadIdx.x;

  if (bid < 4096) {
    const int gid = bid * 256 + tid;
    const int n = gid >> 9, k = gid & 511;
    const float v = ff1_w1[((long)k << 11) | n];
    ff1w1P[((long)(n >> 4) * 16 + (k >> 5)) * 512 + ((k >> 3) & 3) * 128 + (n & 15) * 8 + (k & 7)] = f2bfs(v);
    return;
  }
  bid -= 4096;
  if (bid < 4096) {
    const int gid = bid * 256 + tid;
    const int n = gid >> 11, k = gid & 2047;
    const float v = ff1_w2[(long)k * 512 + n];
    ff1w2P[((long)((n >> 4) << 6) + (k >> 5)) * 512 + ((k >> 3) & 3) * 128 + (n & 15) * 8 + (k & 7)] = f2bfs(v);
    return;
  }
  bid -= 4096;
  if (bid < 3072) {
    const int gid = bid * 256 + tid;
    const int n = gid >> 9, k = gid & 511;
    const int sel = n >> 9;
    const int nn = n & 511;
    const float* w = (sel == 0) ? wq : (sel == 1) ? wk : wv;
    const float v = w[(long)(nn >> 6) * 32768 + (long)k * 64 + (nn & 63)];
    qkvP[((long)(n >> 4) * 16 + (k >> 5)) * 512 + ((k >> 3) & 3) * 128 + (n & 15) * 8 + (k & 7)] = f2bfs(v);
    return;
  }
  bid -= 3072;
  if (bid < 1024) {
    const int gid = bid * 256 + tid;
    const int n = gid >> 9, k = gid & 511;
    const float v = wo[(long)k * 512 + n];
    woP[((long)((n >> 4) << 4) + (k >> 5)) * 512 + ((k >> 3) & 3) * 128 + (n & 15) * 8 + (k & 7)] = f2bfs(v);
    return;
  }
  bid -= 1024;
  if (bid < 2048) {
    const int gid = bid * 256 + tid;
    const int n = gid >> 9, k = gid & 511;
    const float v = cv_w1[((long)n << 9) | k];
    cw1P[((long)(n >> 4) * 16 + (k >> 5)) * 512 + ((k >> 3) & 3) * 128 + (n & 15) * 8 + (k & 7)] = f2bfs(v);
    return;
  }
  bid -= 2048;
  if (bid < 1024) {
    const int gid = bid * 256 + tid;
    const int n = gid >> 9, k = gid & 511;
    const float v = cv_w2[((long)n << 9) | k];
    cw2P[((long)((n >> 4) << 4) + (k >> 5)) * 512 + ((k >> 3) & 3) * 128 + (n & 15) * 8 + (k & 7)] = f2bfs(v);
    return;
  }
  bid -= 1024;
  if (bid < 4096) {
    const int gid = bid * 256 + tid;
    const int n = gid >> 9, k = gid & 511;
    const float v = ff2_w1[((long)k << 11) | n];
    ff2w1P[((long)(n >> 4) * 16 + (k >> 5)) * 512 + ((k >> 3) & 3) * 128 + (n & 15) * 8 + (k & 7)] = f2bfs(v);
    return;
  }
  bid -= 4096;
  if (bid < 4096) {
    const int gid = bid * 256 + tid;
    const int n = gid >> 11, k = gid & 2047;
    const float v = ff2_w2[(long)k * 512 + n];
    ff2w2P[((long)((n >> 4) << 6) + (k >> 5)) * 512 + ((k >> 3) & 3) * 128 + (n & 15) * 8 + (k & 7)] = f2bfs(v);
    return;
  }
  bid -= 4096;
  if (bid < 1024) {
    const int gid = bid * 256 + tid;
    const int e = gid >> 9, i = gid & 511;
    const float* src = cv_wd + ((long)e * 512 + i) * 31;
    const long rowtile = (long)(e >> 4) * (512L * 512);
    const int inner = ((i >> 3) & 3) * 128 + (e & 15) * 8 + (i & 7);
#pragma unroll
    for (int KK = 0; KK < 31; ++KK)
      wdP[rowtile + (long)(KK * 16 + (i >> 5)) * 512 + inner] = f2bfs(src[KK]);
    wdP[rowtile + (long)(31 * 16 + (i >> 5)) * 512 + inner] = 0;
    return;
  }
  bid -= 1024;
  if (bid < 1024) {
    const int gid = bid * 256 + tid;
    const int t = gid >> 8, p = gid & 255;
    const float freq = __expf(-(float)p * (9.210340371976184f / 256.f));
    const float ang = (float)t * freq;
    pe[(long)t * 512 + 2 * p]     = sinf(ang);
    pe[(long)t * 512 + 2 * p + 1] = cosf(ang);
    return;
  }
  *(f32x4*)&stats[tid * 4] = (f32x4){0.f, 0.f, 0.f, 0.f};
}

// ---------------------------------------------------------------------------
// Conv, tap-tiled, B-prefetch depth 3; FM=8/FN=2 waves (round 25, frozen).
// ---------------------------------------------------------------------------
__global__ __launch_bounds__(256) void conv_tap(
    const short* __restrict__ glu,
    const short* __restrict__ wdP,
    short* __restrict__ parts)
{
  __shared__ short sA[2][144 * 32];
  const int tid = threadIdx.x;
  const int bid = blockIdx.x;
  const int cc = bid & 7, j = bid >> 3;
  const int y = cc >> 1, kg = cc & 1;
  const int x = j & 7, b = j >> 3;
  const int m0 = x * 128, n0 = y * 128;
  const short* Arow0 = glu + ((long)b * 1056 + m0 + 1 + kg * 16) * 512;
  short* cbase = parts + (long)kg * (8192L * 512) + (long)b * (1024L * 512);

  const int lane = tid & 63, wid = tid >> 6;
  const int lr = lane & 15, kgr = lane >> 4;
  const int bCol = wid * 32;

  const short* Bp = wdP + (long)((n0 + bCol) >> 4) * (512L * 512)
                  + (long)(kg * 256) * 512 + lane * 8;
  const long NSTR = 512L * 512;

  auto stageA = [&](int buf, int ib) {
#pragma unroll
    for (int it = 0; it < 3; ++it) {
      int idx = it * 256 + tid;
      if (idx < 576) {
        int row = idx >> 2;
        int csrc = (idx & 3) ^ ((row >> 1) & 3);
        GLOADLDS(Arow0 + (long)row * 512 + ib * 32 + csrc * 8,
                 &sA[buf][idx * 8]);
      }
    }
  };

  f32x4 acc[8][2];
#pragma unroll
  for (int i = 0; i < 8; ++i) {
#pragma unroll
    for (int jj = 0; jj < 2; ++jj) acc[i][jj] = (f32x4){0.f, 0.f, 0.f, 0.f};
  }
  short8 bfr[4][2];

#define LOADB(slot_, s_)                                                     \
  {                                                                          \
    const int s2 = (s_);                                                     \
    const long noff = (long)(((s2 & 15) * 16 + (s2 >> 4))) * 512;            \
    _Pragma("unroll")                                                        \
    for (int ni = 0; ni < 2; ++ni)                                           \
      bfr[slot_][ni] = *(const short8*)(Bp + noff + ni * NSTR);              \
  }

  stageA(0, 0);
  MEMFENCE;
  LOADB(0, 0); LOADB(1, 1); LOADB(2, 2);
  MEMFENCE;
  vmcnt_wait<6>();
  __builtin_amdgcn_s_barrier();

  int cur = 0;
  for (int ib = 0; ib < 16; ++ib) {
    if (ib + 1 < 16) stageA(cur ^ 1, ib + 1);
    MEMFENCE;
#pragma unroll
    for (int kk = 0; kk < 16; ++kk) {
      const int s = ib * 16 + kk;
      LOADB((kk + 3) & 3, s + 3);
      MEMFENCE;
      const int aColk = (kgr ^ (((kk + lr) >> 1) & 3)) * 8;
      short8 af[8];
#pragma unroll
      for (int mi = 0; mi < 8; ++mi)
        af[mi] = *(const short8*)&sA[cur][(kk + mi * 16 + lr) * 32 + aColk];
      __builtin_amdgcn_s_setprio(1);
#pragma unroll
      for (int mi = 0; mi < 8; ++mi) {
#pragma unroll
        for (int ni = 0; ni < 2; ++ni)
          acc[mi][ni] = __builtin_amdgcn_mfma_f32_16x16x32_bf16(af[mi], bfr[kk & 3][ni], acc[mi][ni], 0, 0, 0);
      }
      __builtin_amdgcn_s_setprio(0);
    }
    vmcnt_wait<6>();
    __builtin_amdgcn_s_barrier();
    cur ^= 1;
  }
  vmcnt_wait<0>();
#undef LOADB

  const int baseCol = n0 + bCol;
#pragma unroll
  for (int mi = 0; mi < 8; ++mi) {
#pragma unroll
    for (int ni = 0; ni < 2; ++ni) {
      const int col = baseCol + ni * 16 + lr;
#pragma unroll
      for (int r = 0; r < 4; ++r) {
        const int row = m0 + mi * 16 + kgr * 4 + r;
        cbase[(long)row * 512 + col] = f2bfs(acc[mi][ni][r]);
      }
    }
  }
}

// ---------------------------------------------------------------------------
// Flash attention, XCD-pinned flat grid 1024 (round 22, frozen).
// ---------------------------------------------------------------------------
__global__ __launch_bounds__(256) void flash_attn(
    const short* __restrict__ qkv,
    const short* __restrict__ vt,
    short* __restrict__ out)
{
  __shared__ short sQ[64 * 64];
  __shared__ short sK[64 * 64];
  __shared__ short sV[64 * 64];
  __shared__ short sP[4][16 * 64];
  const int tid = threadIdx.x;
  const int lane = tid & 63, w = tid >> 6;
  const int lr = lane & 15, kg = lane >> 4;
  const int bid = (int)blockIdx.x;
  const int xcd = bid & 7, j = bid >> 3;
  const int bhi = j & 7, xq = j >> 3;
  const int bh = bhi * 8 + xcd;
  const int b = bh >> 3, h = bh & 7;
  const int q0 = xq * 64;
  const short* qbase = qkv + (long)b * 1024 * 1536 + h * 64;
  const short* kbase = qbase + 512;
  const short* vtb = vt + (long)bh * 65536;

#pragma unroll
  for (int it = 0; it < 2; ++it) {
    int idx = it * 256 + tid;
    int row = idx >> 3, c = (idx & 7) ^ (row & 7);
    GLOADLDS(qbase + (long)(q0 + row) * 1536 + c * 8, &sQ[idx * 8]);
  }
  __syncthreads();
  short8 bq[2];
#pragma unroll
  for (int ks = 0; ks < 2; ++ks)
    bq[ks] = *(const short8*)&sQ[(w * 16 + lr) * 64 + ((ks * 4 + kg) ^ (lr & 7)) * 8];

  f32x4 po[4];
#pragma unroll
  for (int mi = 0; mi < 4; ++mi) po[mi] = (f32x4){0.f, 0.f, 0.f, 0.f};
  float m = -3.0e38f, l = 0.f;

  for (int s0 = 0; s0 < 1024; s0 += 64) {
#pragma unroll
    for (int it = 0; it < 2; ++it) {
      int idx = it * 256 + tid;
      int row = idx >> 3, c = (idx & 7) ^ (row & 7);
      GLOADLDS(kbase + (long)(s0 + row) * 1536 + c * 8, &sK[idx * 8]);
    }
#pragma unroll
    for (int it = 0; it < 2; ++it) {
      int idx = it * 256 + tid;
      int row = idx >> 3, c = (idx & 7) ^ (row & 7);
      GLOADLDS(vtb + (long)row * 1024 + s0 + c * 8, &sV[idx * 8]);
    }
    __syncthreads();

    f32x4 as[4];
#pragma unroll
    for (int mi = 0; mi < 4; ++mi) as[mi] = (f32x4){0.f, 0.f, 0.f, 0.f};
    __builtin_amdgcn_s_setprio(1);
#pragma unroll
    for (int ks = 0; ks < 2; ++ks) {
#pragma unroll
      for (int mi = 0; mi < 4; ++mi) {
        short8 ak = *(const short8*)&sK[(mi * 16 + lr) * 64 + ((ks * 4 + kg) ^ (lr & 7)) * 8];
        as[mi] = __builtin_amdgcn_mfma_f32_16x16x32_bf16(ak, bq[ks], as[mi], 0, 0, 0);
      }
    }
    __builtin_amdgcn_s_setprio(0);

    float rmax = as[0][0];
#pragma unroll
    for (int mi = 0; mi < 4; ++mi) {
#pragma unroll
      for (int r = 0; r < 4; ++r) rmax = fmaxf(rmax, as[mi][r]);
    }
    rmax = fmaxf(rmax, __shfl_xor(rmax, 16));
    rmax = fmaxf(rmax, __shfl_xor(rmax, 32));
    const float mn = fmaxf(m, rmax);
    const float sc = __expf(m - mn);
    float p[4][4];
    float rsum = 0.f;
#pragma unroll
    for (int mi = 0; mi < 4; ++mi) {
#pragma unroll
      for (int r = 0; r < 4; ++r) { p[mi][r] = __expf(as[mi][r] - mn); rsum += p[mi][r]; }
    }
    rsum += __shfl_xor(rsum, 16);
    rsum += __shfl_xor(rsum, 32);
    l = l * sc + rsum;
    m = mn;
#pragma unroll
    for (int mi = 0; mi < 4; ++mi) {
#pragma unroll
      for (int r = 0; r < 4; ++r) po[mi][r] *= sc;
    }
#pragma unroll
    for (int mi = 0; mi < 4; ++mi) {
      s16x4 pk;
#pragma unroll
      for (int r = 0; r < 4; ++r) pk[r] = f2bfs(p[mi][r]);
      *(s16x4*)&sP[w][lr * 64 + ((mi ^ (lr & 3)) * 16 + kg * 4)] = pk;
    }
    __builtin_amdgcn_s_setprio(1);
#pragma unroll
    for (int ks = 0; ks < 2; ++ks) {
      short8 bp = *(const short8*)&sP[w][lr * 64 + (((ks * 2 + (kg >> 1)) ^ (lr & 3)) * 16 + (kg & 1) * 8)];
#pragma unroll
      for (int mi = 0; mi < 4; ++mi) {
        short8 av = *(const short8*)&sV[(mi * 16 + lr) * 64 + ((ks * 4 + kg) ^ (lr & 7)) * 8];
        po[mi] = __builtin_amdgcn_mfma_f32_16x16x32_bf16(av, bp, po[mi], 0, 0, 0);
      }
    }
    __builtin_amdgcn_s_setprio(0);
    __syncthreads();
  }

  const float inv = 1.f / l;
  const int t2 = q0 + w * 16 + lr;
  const int n = h * 1024 + t2;
  short* ob = out + ((long)b * 1024 + (n >> 3)) * 512 + (n & 7) * 64;
#pragma unroll
  for (int mi = 0; mi < 4; ++mi) {
    s16x4 o;
#pragma unroll
    for (int r = 0; r < 4; ++r) o[r] = f2bfs(po[mi][r] * inv);
    *(s16x4*)&ob[mi * 16 + kg * 4] = o;
  }
}

// ---------------------------------------------------------------------------
__global__ __launch_bounds__(256) void reduce_bn(
    const short* __restrict__ parts, long pstride,
    short* __restrict__ z, float* stats)
{
  const int r0 = blockIdx.x * 16;
  const int c = threadIdx.x * 2;
  float s0 = 0.f, s1 = 0.f, q0 = 0.f, q1 = 0.f;
#pragma unroll 4
  for (int r = 0; r < 16; ++r) {
    const long idx = (long)(r0 + r) * 512 + c;
    int p0 = *(const int*)&parts[idx];
    int p1 = *(const int*)&parts[idx + pstride];
    float a0 = bfs2f((short)(p0 & 0xffff)) + bfs2f((short)(p1 & 0xffff));
    float a1 = bfs2f((short)(p0 >> 16)) + bfs2f((short)(p1 >> 16));
    int zo = ((int)(unsigned short)f2bfs(a0)) | (((int)(unsigned short)f2bfs(a1)) << 16);
    *(int*)&z[idx] = zo;
    s0 += a0; s1 += a1; q0 += a0 * a0; q1 += a1 * a1;
  }
  atomicAdd(&stats[c], s0);
  atomicAdd(&stats[c + 1], s1);
  atomicAdd(&stats[512 + c], q0);
  atomicAdd(&stats[512 + c + 1], q1);
}

// ---------------------------------------------------------------------------
template<int ADDPE, int OUTF32>
__global__ __launch_bounds__(256) void ln_rows(
    const float* __restrict__ X, const float* __restrict__ g, const float* __restrict__ b,
    const float* __restrict__ pe, void* __restrict__ Y)
{
  const int row = blockIdx.x * 4 + (threadIdx.x >> 6);
  const int lane = threadIdx.x & 63;
  const int c0 = lane * 8;
  const float* src = X + (long)row * 512 + c0;
  f32x4 a = *(const f32x4*)src, c = *(const f32x4*)(src + 4);
  float x[8] = {a[0], a[1], a[2], a[3], c[0], c[1], c[2], c[3]};
  float s = 0.f, q = 0.f;
#pragma unroll
  for (int j = 0; j < 8; ++j) { s += x[j]; q += x[j] * x[j]; }
#pragma unroll
  for (int off = 32; off > 0; off >>= 1) { s += __shfl_xor(s, off); q += __shfl_xor(q, off); }
  const float mean = s * (1.f / 512.f);
  const float var = q * (1.f / 512.f) - mean * mean;
  const float rstd = rsqrtf(var + 1e-5f);
  f32x4 g0 = *(const f32x4*)(g + c0), g1 = *(const f32x4*)(g + c0 + 4);
  f32x4 b0 = *(const f32x4*)(b + c0), b1 = *(const f32x4*)(b + c0 + 4);
  float gg[8] = {g0[0], g0[1], g0[2], g0[3], g1[0], g1[1], g1[2], g1[3]};
  float bb[8] = {b0[0], b0[1], b0[2], b0[3], b1[0], b1[1], b1[2], b1[3]};
  float y[8];
#pragma unroll
  for (int j = 0; j < 8; ++j) {
    y[j] = (x[j] - mean) * rstd * gg[j] + bb[j];
    if (ADDPE) y[j] += pe[(long)(row & 1023) * 512 + c0 + j];
  }
  if (OUTF32) {
    float* dst = (float*)Y + (long)row * 512 + c0;
    *(f32x4*)dst = (f32x4){y[0], y[1], y[2], y[3]};
    *(f32x4*)(dst + 4) = (f32x4){y[4], y[5], y[6], y[7]};
  } else {
    short8 o;
#pragma unroll
    for (int j = 0; j < 8; ++j) o[j] = f2bfs(y[j]);
    *(short8*)((short*)Y + (long)row * 512 + c0) = o;
  }
}

// ---------------------------------------------------------------------------
__global__ __launch_bounds__(256) void transpose64b(
    const short* __restrict__ in, int ldin, short* __restrict__ out, int ldout,
    int zshift, long zh_in, long zl_in, long z_out)
{
  __shared__ short t[64][72];
  const int z = blockIdx.z;
  const long inoff = (long)(z >> zshift) * zh_in + (long)(z & ((1 << zshift) - 1)) * zl_in;
  const int tr = blockIdx.x;
  const short* src = in + inoff + (long)(tr * 64) * ldin;
  short* dst = out + (long)z * z_out + tr * 64;
  const int tid = threadIdx.x;
#pragma unroll
  for (int p = 0; p < 2; ++p) {
    int idx = p * 256 + tid;
    int r = idx >> 3, c8 = (idx & 7) * 8;
    short8 v = *(const short8*)(src + (long)r * ldin + c8);
#pragma unroll
    for (int j = 0; j < 8; ++j) t[r][c8 + j] = v[j];
  }
  __syncthreads();
#pragma unroll
  for (int p = 0; p < 2; ++p) {
    int idx = p * 256 + tid;
    int c = idx >> 3, r8 = (idx & 7) * 8;
    short8 v;
#pragma unroll
    for (int j = 0; j < 8; ++j) v[j] = t[r8 + j][c];
    *(short8*)(dst + (long)c * ldout + r8) = v;
  }
}

// ---------------------------------------------------------------------------
// glu + halo zero, fused (round 23, frozen).
// ---------------------------------------------------------------------------
__global__ __launch_bounds__(256) void glu_fused(const short* __restrict__ y1, short* __restrict__ gp)
{
  const int bb = (int)blockIdx.x;
  const int tid = threadIdx.x;
  if (bb < 4096) {
    const int gid = bb * 256 + tid;
    const int row = gid >> 7;
    const int ci = (gid & 127) * 4;
    const short* base = y1 + (long)row * 1024;
    s16x4 a = *(const s16x4*)(base + ci);
    s16x4 g = *(const s16x4*)(base + 512 + ci);
    const int b = row >> 10, t = row & 1023;
    s16x4 o;
#pragma unroll
    for (int j = 0; j < 4; ++j) o[j] = f2bfs(bfs2f(a[j]) * sigmoidf_(bfs2f(g[j])));
    *(s16x4*)(gp + ((long)b * 1056 + 16 + t) * 512 + ci) = o;
    return;
  }
  const int gid = (bb - 4096) * 256 + tid;
  if (gid >= 16512) return;
  long row;
  int c8;
  if (gid < 16384) {
    const int b = gid >> 11;
    const int r = (gid >> 6) & 31;
    c8 = (gid & 63) * 8;
    row = (long)b * 1056 + ((r < 16) ? r : (1024 + r));
  } else {
    const int k = gid - 16384;
    c8 = (k & 63) * 8;
    row = 8448 + (k >> 6);
  }
  *(short8*)(gp + row * 512 + c8) = (short8){0, 0, 0, 0, 0, 0, 0, 0};
}

__global__ void bn_stats(float* stats, const float* __restrict__ bn_g, const float* __restrict__ bn_b)
{
  const int c = blockIdx.x * 256 + threadIdx.x;
  if (c < 512) {
    float mean = stats[c] * (1.f / 8192.f);
    float var = stats[512 + c] * (1.f / 8192.f) - mean * mean;
    float sc = bn_g[c] * rsqrtf(var + 1e-5f);
    stats[1024 + c] = sc;
    stats[1536 + c] = bn_b[c] - mean * sc;
  }
}

__global__ __launch_bounds__(256) void bn_silu(const short* __restrict__ z, const float* __restrict__ stats,
                                               short* __restrict__ out)
{
  const long base = ((long)blockIdx.x * 256 + threadIdx.x) * 8;
  const int c0 = (int)(base & 511);
  short8 v = *(const short8*)(z + base);
  short8 o;
#pragma unroll
  for (int j = 0; j < 8; ++j) {
    const int c = c0 + j;
    float y = bfs2f(v[j]) * stats[1024 + c] + stats[1536 + c];
    o[j] = f2bfs(y * sigmoidf_(y));
  }
  *(short8*)(out + base) = o;
}

// ---------------------------------------------------------------------------
extern "C" void kernel_launch(void* const* d_in, const int* in_sizes, int n_in,
                              void* d_out, int out_size, void* d_ws, size_t ws_size,
                              hipStream_t stream)
{
  (void)in_sizes; (void)n_in; (void)out_size; (void)ws_size;
  const float* x_in   = (const float*)d_in[0];
  const float* ff1_g  = (const float*)d_in[1];
  const float* ff1_bb = (const float*)d_in[2];
  const float* ff1_w1 = (const float*)d_in[3];
  const float* ff1_b1 = (const float*)d_in[4];
  const float* ff1_w2 = (const float*)d_in[5];
  const float* ff1_b2 = (const float*)d_in[6];
  const float* mha_g  = (const float*)d_in[7];
  const float* mha_b  = (const float*)d_in[8];
  const float* wq     = (const float*)d_in[9];
  const float* bq     = (const float*)d_in[10];
  const float* wk     = (const float*)d_in[11];
  const float* bk     = (const float*)d_in[12];
  const float* wv     = (const float*)d_in[13];
  const float* bv     = (const float*)d_in[14];
  const float* wo     = (const float*)d_in[15];
  const float* bo     = (const float*)d_in[16];
  const float* cv_g   = (const float*)d_in[17];
  const float* cv_b   = (const float*)d_in[18];
  const float* cv_w1  = (const float*)d_in[19];
  const float* cv_b1  = (const float*)d_in[20];
  const float* cv_wd  = (const float*)d_in[21];
  const float* bn_g   = (const float*)d_in[22];
  const float* bn_b   = (const float*)d_in[23];
  const float* cv_w2  = (const float*)d_in[24];
  const float* cv_b2  = (const float*)d_in[25];
  const float* ff2_g  = (const float*)d_in[26];
  const float* ff2_b  = (const float*)d_in[27];
  const float* ff2_w1 = (const float*)d_in[28];
  const float* ff2_b1 = (const float*)d_in[29];
  const float* ff2_w2 = (const float*)d_in[30];
  const float* ff2_b2 = (const float*)d_in[31];
  const float* fin_g  = (const float*)d_in[32];
  const float* fin_b  = (const float*)d_in[33];

  size_t off = 0;
  char* wsb = (char*)d_ws;
  auto take = [&](size_t n) { char* p = wsb + off; off += (n + 255) & ~(size_t)255; return p; };
  short* ff1w1P = (short*)take(2048L * 512 * 2);
  short* ff1w2P = (short*)take(2048L * 512 * 2);
  short* qkvP   = (short*)take(1536L * 512 * 2);
  short* woP    = (short*)take(512L * 512 * 2);
  short* cw1P   = (short*)take(1024L * 512 * 2);
  short* cw2P   = (short*)take(512L * 512 * 2);
  short* wdP    = (short*)take(32L * 512 * 512 * 2);
  short* ff2w1P = (short*)take(2048L * 512 * 2);
  short* ff2w2P = (short*)take(2048L * 512 * 2);
  float* xcur   = (float*)take(8192L * 512 * 4);
  char*  Ra     = take(8192L * 2048 * 2);
  short* Rb     = (short*)take(8192L * 512 * 2);
  short* Rg     = (short*)take((8L * 1056 + 2) * 512 * 2);
  short* parts  = (short*)take(2L * 8192 * 512 * 2);
  short* vt     = (short*)take(64L * 64 * 1024 * 2);
  float* pe     = (float*)take(1024L * 512 * 4);
  float* stats  = (float*)take(2048L * 4);

  short* hid = (short*)Ra;
  short* qkv = (short*)Ra;
  short* y1  = (short*)Ra;

  // ---- one-shot prologue: all packs + pe + stats zero ----
  pack_all<<<25601, 256, 0, stream>>>(
      ff1_w1, ff1_w2, wq, wk, wv, wo, cv_w1, cv_w2, ff2_w1, ff2_w2, cv_wd,
      ff1w1P, ff1w2P, qkvP, woP, cw1P, cw2P, ff2w1P, ff2w2P, wdP, pe, stats);

  // ---- FF1: x1 = 1.5 x + 0.5 (silu(ln(x) W1 + b1) W2 + b2) ----
  ln_rows<0, 0><<<2048, 256, 0, stream>>>(x_in, ff1_g, ff1_bb, nullptr, Rb);
  gemm_bdw<16, EPI_SILU><<<dim3(64, 16), 256, 0, stream>>>(
      Rb, ff1w1P, ff1_b1, nullptr, nullptr, hid);
  gemm_bd<64><<<512, 256, 0, stream>>>(hid, ff1w2P, ff1_b2, x_in, xcur, 1.5f, 0.5f);

  // ---- MHSA: x2 = 2 x1 + (scramble(attn) Wo + bo) ----
  ln_rows<1, 0><<<2048, 256, 0, stream>>>(xcur, mha_g, mha_b, pe, Rb);
  gemm_bdw<12, EPI_QKV><<<dim3(64, 12), 256, 0, stream>>>(
      Rb, qkvP, bq, bk, bv, qkv);
  transpose64b<<<dim3(16, 1, 64), 256, 0, stream>>>(qkv + 1024, 1536, vt, 1024, 3,
                                                    1024L * 1536, 64, 65536);
  flash_attn<<<1024, 256, 0, stream>>>(qkv, vt, Rb);
  gemm_bd<16><<<512, 256, 0, stream>>>(Rb, woP, bo, xcur, xcur, 2.f, 1.f);

  // ---- Conv module ----
  ln_rows<0, 0><<<2048, 256, 0, stream>>>(xcur, cv_g, cv_b, nullptr, Rb);
  gemm_bdw<8, EPI_BBIAS><<<dim3(64, 8), 256, 0, stream>>>(
      Rb, cw1P, cv_b1, nullptr, nullptr, y1);
  glu_fused<<<4161, 256, 0, stream>>>(y1, Rg);
  conv_tap<<<512, 256, 0, stream>>>(Rg, wdP, parts);
  reduce_bn<<<512, 256, 0, stream>>>(parts, 8192L * 512, Rb, stats);
  bn_stats<<<2, 256, 0, stream>>>(stats, bn_g, bn_b);
  bn_silu<<<2048, 256, 0, stream>>>(Rb, stats, (short*)Rg);
  gemm_bd<16><<<512, 256, 0, stream>>>((short*)Rg, cw2P, cv_b2, xcur, xcur, 2.f, 1.f);

  // ---- FF2 ----
  ln_rows<0, 0><<<2048, 256, 0, stream>>>(xcur, ff2_g, ff2_b, nullptr, Rb);
  gemm_bdw<16, EPI_SILU><<<dim3(64, 16), 256, 0, stream>>>(
      Rb, ff2w1P, ff2_b1, nullptr, nullptr, hid);
  gemm_bd<64><<<512, 256, 0, stream>>>(hid, ff2w2P, ff2_b2, xcur, xcur, 1.5f, 0.5f);

  // ---- final LN -> d_out (fp32) ----
  ln_rows<0, 1><<<2048, 256, 0, stream>>>(xcur, fin_g, fin_b, nullptr, (float*)d_out);
}